// Round 6
// baseline (205.384 us; speedup 1.0000x reference)
//
#include <hip/hip_runtime.h>
#include <hip/hip_bf16.h>

#define HID 128
#define OUTC 64
#define INC 3
#define BCAP 64        // bucket capacity per node (storage only; degree is exact)
#define OVF_CAP 8192   // overflow edge list capacity (expected usage: 0)
#define NT 64          // nodes per block in hidden GEMM
#define NCBMAX 256     // max coarse buckets (N<=65535 -> NCB<=256)
#define NB1 128        // blocks for hist/place passes
#define EPT 4          // legacy path

static __device__ __forceinline__ unsigned short f2bf(float f) {
    __hip_bfloat16 b = __float2bfloat16(f);
    return *reinterpret_cast<unsigned short*>(&b);
}
static __device__ __forceinline__ float bf2f(unsigned short u) {
    __hip_bfloat16 b = *reinterpret_cast<__hip_bfloat16*>(&u);
    return __bfloat162float(b);
}

// ================= two-level counting-sort bucket build (N <= 65535 path) =================

// pass 1: per-block histogram of coarse bucket (dst>>8)
__global__ void hist_kernel(const int* __restrict__ dst, int E, int chunk, int NCB,
                            int* __restrict__ blockhist) {
    __shared__ int hist[NCBMAX];
    int t = threadIdx.x;
    for (int i = t; i < NCBMAX; i += 256) hist[i] = 0;
    __syncthreads();
    int s0 = blockIdx.x * chunk;
    int s1 = min(E, s0 + chunk);
    for (int e = s0 + t; e < s1; e += 256) atomicAdd(&hist[dst[e] >> 8], 1);
    __syncthreads();
    for (int i = t; i < NCB; i += 256) blockhist[blockIdx.x * NCB + i] = hist[i];
}

// pass 2 (1 block): exact per-coarse-bucket offsets and per-block write bases
__global__ void scan_kernel(int* __restrict__ blockhist, int NB, int NCB,
                            int* __restrict__ cboff, int* __restrict__ cbcnt) {
    __shared__ int tot[NCBMAX];
    __shared__ int off[NCBMAX];
    int t = threadIdx.x;
    int s = 0;
    if (t < NCB) for (int b = 0; b < NB; ++b) s += blockhist[b * NCB + t];
    if (t < NCBMAX) tot[t] = (t < NCB) ? s : 0;
    __syncthreads();
    if (t == 0) { int r = 0; for (int i = 0; i < NCB; ++i) { off[i] = r; r += tot[i]; } }
    __syncthreads();
    if (t < NCB) {
        cboff[t] = off[t];
        cbcnt[t] = tot[t];
        int r = off[t];
        for (int b = 0; b < NB; ++b) {
            int c = blockhist[b * NCB + t];
            blockhist[b * NCB + t] = r;
            r += c;
        }
    }
}

// pass 3: place packed (src | local_dst<<16) into coarse-partitioned array (dense-ish writes)
__global__ void place_kernel(const int* __restrict__ src, const int* __restrict__ dst, int E,
                             int chunk, int NCB, const int* __restrict__ blockhist,
                             unsigned int* __restrict__ part) {
    __shared__ int base[NCBMAX];
    __shared__ int lofs[NCBMAX];
    int t = threadIdx.x;
    for (int i = t; i < NCB; i += 256) { base[i] = blockhist[blockIdx.x * NCB + i]; lofs[i] = 0; }
    __syncthreads();
    int s0 = blockIdx.x * chunk;
    int s1 = min(E, s0 + chunk);
    for (int e = s0 + t; e < s1; e += 256) {
        int d = dst[e], s = src[e];
        int cb = d >> 8;
        int p = atomicAdd(&lofs[cb], 1);
        part[base[cb] + p] = (unsigned)s | ((unsigned)(d & 255) << 16);
    }
}

// pass 4: one block per coarse bucket — LDS binning, then dense 32KB bucket write;
// fuses exact degree -> cursor and z4 = (dinv*x, dinv)
__global__ __launch_bounds__(256) void bin_kernel(const unsigned int* __restrict__ part,
                                                  const int* __restrict__ cboff,
                                                  const int* __restrict__ cbcnt,
                                                  const float* __restrict__ x, int N,
                                                  int* __restrict__ cursor,
                                                  unsigned short* __restrict__ bucket,
                                                  float4* __restrict__ z4,
                                                  int* __restrict__ ovf, int* __restrict__ ovf_cnt) {
    __shared__ int lcnt[256];
    __shared__ unsigned short lbuck[256 * BCAP];   // 32 KB
    int cb = blockIdx.x, t = threadIdx.x;
    lcnt[t] = 0;
    __syncthreads();
    int start = cboff[cb], cnt = cbcnt[cb];
    for (int i = t; i < cnt; i += 256) {
        unsigned pk = part[start + i];
        int s = pk & 0xFFFF;
        int ln = (pk >> 16) & 0xFF;
        int p = atomicAdd(&lcnt[ln], 1);
        if (p < BCAP) {
            lbuck[ln * BCAP + p] = (unsigned short)s;
        } else {
            int o = atomicAdd(ovf_cnt, 1);
            if (o < OVF_CAP) { ovf[2 * o] = s; ovf[2 * o + 1] = cb * 256 + ln; }
        }
    }
    __syncthreads();
    int d = cb * 256 + t;
    if (d < N) {
        int deg = lcnt[t];                         // exact degree (incl. >BCAP spill)
        cursor[d] = deg;
        float dd = rsqrtf((float)(deg + 1));       // +1 = self loop
        z4[d] = make_float4(dd * x[3 * d], dd * x[3 * d + 1], dd * x[3 * d + 2], dd);
    }
    const uint4* lsrc = (const uint4*)lbuck;
    uint4* gdst = (uint4*)(bucket + (size_t)cb * 256 * BCAP);
    for (int i = t; i < (256 * BCAP * 2) / 16; i += 256) gdst[i] = lsrc[i];  // dense copy
}

// ================= legacy path (N > 65535): atomic fill + z4 =================

template <typename IT>
__global__ void fill_bucket_kernel(const int* __restrict__ src, const int* __restrict__ dst, int E,
                                   int T, int* __restrict__ cursor, IT* __restrict__ bucket,
                                   int* __restrict__ ovf, int* __restrict__ ovf_cnt) {
    int tid = blockIdx.x * blockDim.x + threadIdx.x;
    int d[EPT], s[EPT], p[EPT];
    bool v[EPT];
#pragma unroll
    for (int k = 0; k < EPT; ++k) {
        int e = tid + k * T;
        v[k] = (e < E);
        d[k] = v[k] ? dst[e] : 0;
        s[k] = v[k] ? src[e] : 0;
    }
#pragma unroll
    for (int k = 0; k < EPT; ++k)
        if (v[k]) p[k] = atomicAdd(&cursor[d[k]], 1);
#pragma unroll
    for (int k = 0; k < EPT; ++k) {
        if (v[k]) {
            if (p[k] < BCAP) {
                bucket[(size_t)d[k] * BCAP + p[k]] = (IT)s[k];
            } else {
                int o = atomicAdd(ovf_cnt, 1);
                if (o < OVF_CAP) { ovf[2 * o] = s[k]; ovf[2 * o + 1] = d[k]; }
            }
        }
    }
}

__global__ void z4_kernel(const float* __restrict__ x, const int* __restrict__ cursor,
                          float4* __restrict__ z4, int N) {
    int i = blockIdx.x * blockDim.x + threadIdx.x;
    if (i < N) {
        float dd = rsqrtf((float)(cursor[i] + 1));
        z4[i] = make_float4(dd * x[3 * i], dd * x[3 * i + 1], dd * x[3 * i + 2], dd);
    }
}

// ================= layer-1 aggregation: agg4[d] = sum z4[s].xyz =================

template <typename IT>
__global__ void gather1_kernel(const int* __restrict__ cursor, const IT* __restrict__ bucket,
                               const float4* __restrict__ z4, float4* __restrict__ agg4, int N) {
    int wid = threadIdx.x >> 6;
    int j = threadIdx.x & 63;
    int d = blockIdx.x * 4 + wid;
    if (d >= N) return;
    int cnt = cursor[d];
    cnt = cnt < BCAP ? cnt : BCAP;
    float a0 = 0.f, a1 = 0.f, a2 = 0.f;
    if (j < cnt) {
        int s = (int)bucket[(size_t)d * BCAP + j];
        float4 zv = z4[s];
        a0 = zv.x; a1 = zv.y; a2 = zv.z;
    }
#pragma unroll
    for (int o = 32; o > 0; o >>= 1) {
        a0 += __shfl_xor(a0, o, 64);
        a1 += __shfl_xor(a1, o, 64);
        a2 += __shfl_xor(a2, o, 64);
    }
    if (j == 0) agg4[d] = make_float4(a0, a1, a2, 0.f);
}

__global__ void ovf1_kernel(const int* __restrict__ ovf, const int* __restrict__ ovf_cnt,
                            const float4* __restrict__ z4, float4* __restrict__ agg4) {
    int cnt = *ovf_cnt;
    cnt = cnt < OVF_CAP ? cnt : OVF_CAP;
    for (int t = threadIdx.x; t < cnt; t += blockDim.x) {
        int s = ovf[2 * t], d = ovf[2 * t + 1];
        float4 zv = z4[s];
        float* a = (float*)&agg4[d];
        atomicAdd(a + 0, zv.x);
        atomicAdd(a + 1, zv.y);
        atomicAdd(a + 2, zv.z);
    }
}

// ============ fused hidden GEMM: u -> relu(u@W1+b1) -> hs2 = dinv*(h@W2), bf16 out ============

__global__ __launch_bounds__(256) void hidden_kernel(const float4* __restrict__ agg4,
                                                     const float4* __restrict__ z4,
                                                     const float* __restrict__ W1,
                                                     const float* __restrict__ b1,
                                                     const float* __restrict__ W2,
                                                     unsigned short* __restrict__ hs2b, int N) {
    __shared__ float h_s[HID][NT];       // 32 KB, k-major
    __shared__ float w_s[HID * OUTC];    // 32 KB
    int t = threadIdx.x;
    int base = blockIdx.x * NT;

    for (int i = t; i < HID * OUTC; i += 256) w_s[i] = W2[i];

    {
        int n = t & 63;
        int d = base + n;
        float u0 = 0.f, u1 = 0.f, u2 = 0.f;
        if (d < N) {
            float4 zv = z4[d];
            float4 av = agg4[d];
            float dd = zv.w;
            u0 = dd * (av.x + zv.x);
            u1 = dd * (av.y + zv.y);
            u2 = dd * (av.z + zv.z);
        }
        int k0 = t >> 6;
#pragma unroll
        for (int i = 0; i < HID / 4; ++i) {
            int k = k0 + 4 * i;
            float v = u0 * W1[k] + u1 * W1[HID + k] + u2 * W1[2 * HID + k] + b1[k];
            h_s[k][n] = fmaxf(v, 0.f);
        }
    }
    __syncthreads();

    int tx = t & 15, ty = t >> 4;
    float acc[4][4] = {};
#pragma unroll 8
    for (int k = 0; k < HID; ++k) {
        float4 hv = *(const float4*)&h_s[k][ty * 4];
        float4 wv = *(const float4*)&w_s[k * OUTC + tx * 4];
        float hr[4] = {hv.x, hv.y, hv.z, hv.w};
        float wr[4] = {wv.x, wv.y, wv.z, wv.w};
#pragma unroll
        for (int r = 0; r < 4; ++r)
#pragma unroll
            for (int c = 0; c < 4; ++c) acc[r][c] = fmaf(hr[r], wr[c], acc[r][c]);
    }

#pragma unroll
    for (int r = 0; r < 4; ++r) {
        int n = ty * 4 + r;
        int d = base + n;
        if (d < N) {
            float dd = z4[d].w;
            ushort4 o;
            o.x = f2bf(dd * acc[r][0]);
            o.y = f2bf(dd * acc[r][1]);
            o.z = f2bf(dd * acc[r][2]);
            o.w = f2bf(dd * acc[r][3]);
            *(ushort4*)&hs2b[(size_t)d * OUTC + tx * 4] = o;
        }
    }
}

// ============ layer-2 gather: out[d] = dinv[d]*(sum hs2[s] + hs2[d]) + b2 ============

template <typename IT>
__global__ void gather2_kernel(const int* __restrict__ cursor, const IT* __restrict__ bucket,
                               const unsigned short* __restrict__ hs2b, const float4* __restrict__ z4,
                               const float* __restrict__ b2, float* __restrict__ out, int N) {
    int wid = threadIdx.x >> 6;
    int j = threadIdx.x & 63;
    int d = blockIdx.x * 4 + wid;
    if (d >= N) return;
    int cnt = cursor[d];
    cnt = cnt < BCAP ? cnt : BCAP;
    int sv = (j < cnt) ? (int)bucket[(size_t)d * BCAP + j] : 0;
    float acc = 0.0f;
    int k = 0;
    for (; k + 4 <= cnt; k += 4) {
        int s0 = __shfl(sv, k, 64), s1 = __shfl(sv, k + 1, 64);
        int s2 = __shfl(sv, k + 2, 64), s3 = __shfl(sv, k + 3, 64);
        float v0 = bf2f(hs2b[(size_t)s0 * OUTC + j]);
        float v1 = bf2f(hs2b[(size_t)s1 * OUTC + j]);
        float v2 = bf2f(hs2b[(size_t)s2 * OUTC + j]);
        float v3 = bf2f(hs2b[(size_t)s3 * OUTC + j]);
        acc += (v0 + v1) + (v2 + v3);
    }
    for (; k < cnt; ++k) {
        int s = __shfl(sv, k, 64);
        acc += bf2f(hs2b[(size_t)s * OUTC + j]);
    }
    float dd = z4[d].w;
    out[(size_t)d * OUTC + j] = dd * (acc + bf2f(hs2b[(size_t)d * OUTC + j])) + b2[j];
}

__global__ void ovf2_kernel(const int* __restrict__ ovf, const int* __restrict__ ovf_cnt,
                            const unsigned short* __restrict__ hs2b, const float4* __restrict__ z4,
                            float* __restrict__ out) {
    int cnt = *ovf_cnt;
    cnt = cnt < OVF_CAP ? cnt : OVF_CAP;
    for (int t = threadIdx.x; t < cnt * OUTC; t += blockDim.x) {
        int o = t >> 6, j = t & 63;
        int s = ovf[2 * o], d = ovf[2 * o + 1];
        atomicAdd(&out[(size_t)d * OUTC + j], z4[d].w * bf2f(hs2b[(size_t)s * OUTC + j]));
    }
}

static inline size_t align256(size_t v) { return (v + 255) & ~(size_t)255; }

extern "C" void kernel_launch(void* const* d_in, const int* in_sizes, int n_in,
                              void* d_out, int out_size, void* d_ws, size_t ws_size,
                              hipStream_t stream) {
    const float* x  = (const float*)d_in[0];
    const int*   ei = (const int*)d_in[1];
    const float* W1 = (const float*)d_in[2];
    const float* b1 = (const float*)d_in[3];
    const float* W2 = (const float*)d_in[4];
    const float* b2 = (const float*)d_in[5];
    float* out = (float*)d_out;

    const int N = in_sizes[0] / INC;
    const int E = in_sizes[1] / 2;
    const int* src = ei;
    const int* dst = ei + E;
    const bool u16 = (N <= 65535);
    const int NCB = (N + 255) >> 8;

    char* ws = (char*)d_ws;
    size_t off = 0;
    int*    cursor  = (int*)(ws + off);    off += align256((size_t)N * 4);
    float4* z4      = (float4*)(ws + off); off += align256((size_t)N * 16);
    float4* agg4    = (float4*)(ws + off); off += align256((size_t)N * 16);
    int*    ovf_cnt = (int*)(ws + off);    off += 256;
    int*    ovf     = (int*)(ws + off);    off += (size_t)OVF_CAP * 8;
    int*    cboff   = (int*)(ws + off);    off += align256((size_t)NCBMAX * 4);
    int*    cbcnt   = (int*)(ws + off);    off += align256((size_t)NCBMAX * 4);
    int*    blockhist = (int*)(ws + off);  off += align256((size_t)NB1 * NCBMAX * 4);
    unsigned int* part = (unsigned int*)(ws + off); off += align256((size_t)E * 4);
    void*   bucket  = (void*)(ws + off);
    off += align256(u16 ? (size_t)NCB * 256 * BCAP * 2 : (size_t)N * BCAP * 4);
    unsigned short* hs2b = (unsigned short*)(ws + off); off += (size_t)N * OUTC * 2;

    const int B = 256;

    hipMemsetAsync(ovf_cnt, 0, 64, stream);

    if (u16) {
        int chunk = (E + NB1 - 1) / NB1;
        hist_kernel<<<NB1, B, 0, stream>>>(dst, E, chunk, NCB, blockhist);
        scan_kernel<<<1, B, 0, stream>>>(blockhist, NB1, NCB, cboff, cbcnt);
        place_kernel<<<NB1, B, 0, stream>>>(src, dst, E, chunk, NCB, blockhist, part);
        bin_kernel<<<NCB, B, 0, stream>>>(part, cboff, cbcnt, x, N, cursor,
                                          (unsigned short*)bucket, z4, ovf, ovf_cnt);
    } else {
        hipMemsetAsync(cursor, 0, (size_t)N * sizeof(int), stream);
        int grid = (E + B * EPT - 1) / (B * EPT);
        int T = grid * B;
        fill_bucket_kernel<int><<<grid, B, 0, stream>>>(src, dst, E, T, cursor, (int*)bucket,
                                                        ovf, ovf_cnt);
        z4_kernel<<<(N + B - 1) / B, B, 0, stream>>>(x, cursor, z4, N);
    }

    // ---- layer 1 (3-dim gather aggregation, no atomics) ----
    if (u16)
        gather1_kernel<unsigned short><<<(N + 3) / 4, B, 0, stream>>>(
            cursor, (const unsigned short*)bucket, z4, agg4, N);
    else
        gather1_kernel<int><<<(N + 3) / 4, B, 0, stream>>>(
            cursor, (const int*)bucket, z4, agg4, N);
    ovf1_kernel<<<1, B, 0, stream>>>(ovf, ovf_cnt, z4, agg4);

    // ---- fused hidden (relu(u@W1+b1) @ W2, register-tiled GEMM, bf16 out) ----
    hidden_kernel<<<(N + NT - 1) / NT, 256, 0, stream>>>(agg4, z4, W1, b1, W2, hs2b, N);

    // ---- layer 2 gather ----
    if (u16)
        gather2_kernel<unsigned short><<<(N + 3) / 4, B, 0, stream>>>(
            cursor, (const unsigned short*)bucket, hs2b, z4, b2, out, N);
    else
        gather2_kernel<int><<<(N + 3) / 4, B, 0, stream>>>(
            cursor, (const int*)bucket, hs2b, z4, b2, out, N);
    ovf2_kernel<<<1, B, 0, stream>>>(ovf, ovf_cnt, hs2b, z4, out);
}

// Round 8
// 172.096 us; speedup vs baseline: 1.1934x; 1.1934x over previous
//
#include <hip/hip_runtime.h>
#include <hip/hip_bf16.h>

#define HID 128
#define OUTC 64
#define INC 3
#define BCAP 64        // bucket capacity per node (storage only; degree is exact)
#define OVF_CAP 8192   // overflow edge list capacity (expected usage: 0)
#define NT 64          // nodes per block in hidden GEMM
#define NCBMAX 256     // max coarse buckets (N<=65535 -> NCB<=256)
#define NB1 128        // blocks for hist/place passes
#define EPT 4          // legacy path

static __device__ __forceinline__ unsigned short f2bf(float f) {
    __hip_bfloat16 b = __float2bfloat16(f);
    return *reinterpret_cast<unsigned short*>(&b);
}
static __device__ __forceinline__ float bf2f(unsigned short u) {
    __hip_bfloat16 b = *reinterpret_cast<__hip_bfloat16*>(&u);
    return __bfloat162float(b);
}

// ================= two-level counting-sort bucket build (N <= 65535 path) =================

// pass 1: per-block histogram of coarse bucket (dst>>8)   [round-6 proven]
__global__ void hist_kernel(const int* __restrict__ dst, int E, int chunk, int NCB,
                            int* __restrict__ blockhist) {
    __shared__ int hist[NCBMAX];
    int t = threadIdx.x;
    for (int i = t; i < NCBMAX; i += 256) hist[i] = 0;
    __syncthreads();
    int s0 = blockIdx.x * chunk;
    int s1 = min(E, s0 + chunk);
    for (int e = s0 + t; e < s1; e += 256) atomicAdd(&hist[dst[e] >> 8], 1);
    __syncthreads();
    for (int i = t; i < NCB; i += 256) blockhist[blockIdx.x * NCB + i] = hist[i];
}

// pass 2a (1 block): per-bucket totals (independent strided loads, MLP) + LDS prefix
__global__ void scanA_kernel(const int* __restrict__ blockhist, int NB, int NCB,
                             int* __restrict__ cboff, int* __restrict__ cbcnt) {
    __shared__ int v[NCBMAX];
    int t = threadIdx.x;
    int s = 0;
    if (t < NCB) {
#pragma unroll 8
        for (int b = 0; b < NB; ++b) s += blockhist[b * NCB + t];   // independent loads
    }
    v[t] = (t < NCB) ? s : 0;
    __syncthreads();
    for (int o = 1; o < NCBMAX; o <<= 1) {
        int add = (t >= o) ? v[t - o] : 0;
        __syncthreads();
        v[t] += add;
        __syncthreads();
    }
    if (t < NCB) { cboff[t] = v[t] - s; cbcnt[t] = s; }
}

// pass 2b (NCB blocks x NB1 threads): per-(block,bucket) write bases =
// cboff[bucket] + exclusive prefix over blocks — same output as round-6 serial scan
__global__ void scanB_kernel(int* __restrict__ blockhist, int NCB,
                             const int* __restrict__ cboff) {
    __shared__ int v[NB1];
    int i = blockIdx.x;     // bucket
    int t = threadIdx.x;    // block index
    int c = blockhist[t * NCB + i];
    v[t] = c;
    __syncthreads();
    for (int o = 1; o < NB1; o <<= 1) {
        int add = (t >= o) ? v[t - o] : 0;
        __syncthreads();
        v[t] += add;
        __syncthreads();
    }
    blockhist[t * NCB + i] = cboff[i] + v[t] - c;
}

// pass 3: place packed (src | local_dst<<16) into coarse-partitioned array   [round-6 proven]
__global__ void place_kernel(const int* __restrict__ src, const int* __restrict__ dst, int E,
                             int chunk, int NCB, const int* __restrict__ blockhist,
                             unsigned int* __restrict__ part) {
    __shared__ int base[NCBMAX];
    __shared__ int lofs[NCBMAX];
    int t = threadIdx.x;
    for (int i = t; i < NCB; i += 256) { base[i] = blockhist[blockIdx.x * NCB + i]; lofs[i] = 0; }
    __syncthreads();
    int s0 = blockIdx.x * chunk;
    int s1 = min(E, s0 + chunk);
    for (int e = s0 + t; e < s1; e += 256) {
        int d = dst[e], s = src[e];
        int cb = d >> 8;
        int p = atomicAdd(&lofs[cb], 1);
        part[base[cb] + p] = (unsigned)s | ((unsigned)(d & 255) << 16);
    }
}

// pass 4: one block per coarse bucket — LDS binning, dense 32KB bucket write;
// fuses exact degree -> cursor and z4 = (dinv*x, dinv)   [round-6 proven]
__global__ __launch_bounds__(256) void bin_kernel(const unsigned int* __restrict__ part,
                                                  const int* __restrict__ cboff,
                                                  const int* __restrict__ cbcnt,
                                                  const float* __restrict__ x, int N,
                                                  int* __restrict__ cursor,
                                                  unsigned short* __restrict__ bucket,
                                                  float4* __restrict__ z4,
                                                  int* __restrict__ ovf, int* __restrict__ ovf_cnt) {
    __shared__ int lcnt[256];
    __shared__ unsigned short lbuck[256 * BCAP];   // 32 KB
    int cb = blockIdx.x, t = threadIdx.x;
    lcnt[t] = 0;
    __syncthreads();
    int start = cboff[cb], cnt = cbcnt[cb];
    for (int i = t; i < cnt; i += 256) {
        unsigned pk = part[start + i];
        int s = pk & 0xFFFF;
        int ln = (pk >> 16) & 0xFF;
        int p = atomicAdd(&lcnt[ln], 1);
        if (p < BCAP) {
            lbuck[ln * BCAP + p] = (unsigned short)s;
        } else {
            int o = atomicAdd(ovf_cnt, 1);
            if (o < OVF_CAP) { ovf[2 * o] = s; ovf[2 * o + 1] = cb * 256 + ln; }
        }
    }
    __syncthreads();
    int d = cb * 256 + t;
    if (d < N) {
        int deg = lcnt[t];                         // exact degree (incl. >BCAP spill)
        cursor[d] = deg;
        float dd = rsqrtf((float)(deg + 1));       // +1 = self loop
        z4[d] = make_float4(dd * x[3 * d], dd * x[3 * d + 1], dd * x[3 * d + 2], dd);
    }
    const uint4* lsrc = (const uint4*)lbuck;
    uint4* gdst = (uint4*)(bucket + (size_t)cb * 256 * BCAP);
    for (int i = t; i < (256 * BCAP * 2) / 16; i += 256) gdst[i] = lsrc[i];  // dense copy
}

// ================= legacy path (N > 65535): atomic fill + z4 =================

template <typename IT>
__global__ void fill_bucket_kernel(const int* __restrict__ src, const int* __restrict__ dst, int E,
                                   int T, int* __restrict__ cursor, IT* __restrict__ bucket,
                                   int* __restrict__ ovf, int* __restrict__ ovf_cnt) {
    int tid = blockIdx.x * blockDim.x + threadIdx.x;
    int d[EPT], s[EPT], p[EPT];
    bool v[EPT];
#pragma unroll
    for (int k = 0; k < EPT; ++k) {
        int e = tid + k * T;
        v[k] = (e < E);
        d[k] = v[k] ? dst[e] : 0;
        s[k] = v[k] ? src[e] : 0;
    }
#pragma unroll
    for (int k = 0; k < EPT; ++k)
        if (v[k]) p[k] = atomicAdd(&cursor[d[k]], 1);
#pragma unroll
    for (int k = 0; k < EPT; ++k) {
        if (v[k]) {
            if (p[k] < BCAP) {
                bucket[(size_t)d[k] * BCAP + p[k]] = (IT)s[k];
            } else {
                int o = atomicAdd(ovf_cnt, 1);
                if (o < OVF_CAP) { ovf[2 * o] = s[k]; ovf[2 * o + 1] = d[k]; }
            }
        }
    }
}

__global__ void z4_kernel(const float* __restrict__ x, const int* __restrict__ cursor,
                          float4* __restrict__ z4, int N) {
    int i = blockIdx.x * blockDim.x + threadIdx.x;
    if (i < N) {
        float dd = rsqrtf((float)(cursor[i] + 1));
        z4[i] = make_float4(dd * x[3 * i], dd * x[3 * i + 1], dd * x[3 * i + 2], dd);
    }
}

// ================= layer-1 aggregation: agg4[d] = sum z4[s].xyz   [round-6 proven] ==========

template <typename IT>
__global__ void gather1_kernel(const int* __restrict__ cursor, const IT* __restrict__ bucket,
                               const float4* __restrict__ z4, float4* __restrict__ agg4, int N) {
    int wid = threadIdx.x >> 6;
    int j = threadIdx.x & 63;
    int d = blockIdx.x * 4 + wid;
    if (d >= N) return;
    int cnt = cursor[d];
    cnt = cnt < BCAP ? cnt : BCAP;
    float a0 = 0.f, a1 = 0.f, a2 = 0.f;
    if (j < cnt) {
        int s = (int)bucket[(size_t)d * BCAP + j];
        float4 zv = z4[s];
        a0 = zv.x; a1 = zv.y; a2 = zv.z;
    }
#pragma unroll
    for (int o = 32; o > 0; o >>= 1) {
        a0 += __shfl_xor(a0, o, 64);
        a1 += __shfl_xor(a1, o, 64);
        a2 += __shfl_xor(a2, o, 64);
    }
    if (j == 0) agg4[d] = make_float4(a0, a1, a2, 0.f);
}

__global__ void ovf1_kernel(const int* __restrict__ ovf, const int* __restrict__ ovf_cnt,
                            const float4* __restrict__ z4, float4* __restrict__ agg4) {
    int cnt = *ovf_cnt;
    cnt = cnt < OVF_CAP ? cnt : OVF_CAP;
    for (int t = threadIdx.x; t < cnt; t += blockDim.x) {
        int s = ovf[2 * t], d = ovf[2 * t + 1];
        float4 zv = z4[s];
        float* a = (float*)&agg4[d];
        atomicAdd(a + 0, zv.x);
        atomicAdd(a + 1, zv.y);
        atomicAdd(a + 2, zv.z);
    }
}

// ============ fused hidden GEMM: u -> relu(u@W1+b1) -> hs2 = dinv*(h@W2), bf16 out ============

__global__ __launch_bounds__(256) void hidden_kernel(const float4* __restrict__ agg4,
                                                     const float4* __restrict__ z4,
                                                     const float* __restrict__ W1,
                                                     const float* __restrict__ b1,
                                                     const float* __restrict__ W2,
                                                     unsigned short* __restrict__ hs2b, int N) {
    __shared__ float h_s[HID][NT];       // 32 KB, k-major
    __shared__ float w_s[HID * OUTC];    // 32 KB
    int t = threadIdx.x;
    int base = blockIdx.x * NT;

    for (int i = t; i < HID * OUTC; i += 256) w_s[i] = W2[i];

    {
        int n = t & 63;
        int d = base + n;
        float u0 = 0.f, u1 = 0.f, u2 = 0.f;
        if (d < N) {
            float4 zv = z4[d];
            float4 av = agg4[d];
            float dd = zv.w;
            u0 = dd * (av.x + zv.x);
            u1 = dd * (av.y + zv.y);
            u2 = dd * (av.z + zv.z);
        }
        int k0 = t >> 6;
#pragma unroll
        for (int i = 0; i < HID / 4; ++i) {
            int k = k0 + 4 * i;
            float v = u0 * W1[k] + u1 * W1[HID + k] + u2 * W1[2 * HID + k] + b1[k];
            h_s[k][n] = fmaxf(v, 0.f);
        }
    }
    __syncthreads();

    int tx = t & 15, ty = t >> 4;
    float acc[4][4] = {};
#pragma unroll 8
    for (int k = 0; k < HID; ++k) {
        float4 hv = *(const float4*)&h_s[k][ty * 4];
        float4 wv = *(const float4*)&w_s[k * OUTC + tx * 4];
        float hr[4] = {hv.x, hv.y, hv.z, hv.w};
        float wr[4] = {wv.x, wv.y, wv.z, wv.w};
#pragma unroll
        for (int r = 0; r < 4; ++r)
#pragma unroll
            for (int c = 0; c < 4; ++c) acc[r][c] = fmaf(hr[r], wr[c], acc[r][c]);
    }

#pragma unroll
    for (int r = 0; r < 4; ++r) {
        int n = ty * 4 + r;
        int d = base + n;
        if (d < N) {
            float dd = z4[d].w;
            ushort4 o;
            o.x = f2bf(dd * acc[r][0]);
            o.y = f2bf(dd * acc[r][1]);
            o.z = f2bf(dd * acc[r][2]);
            o.w = f2bf(dd * acc[r][3]);
            *(ushort4*)&hs2b[(size_t)d * OUTC + tx * 4] = o;
        }
    }
}

// ============ layer-2 gather: out[d] = dinv[d]*(sum hs2[s] + hs2[d]) + b2   [round-6 proven] ==

template <typename IT>
__global__ void gather2_kernel(const int* __restrict__ cursor, const IT* __restrict__ bucket,
                               const unsigned short* __restrict__ hs2b, const float4* __restrict__ z4,
                               const float* __restrict__ b2, float* __restrict__ out, int N) {
    int wid = threadIdx.x >> 6;
    int j = threadIdx.x & 63;
    int d = blockIdx.x * 4 + wid;
    if (d >= N) return;
    int cnt = cursor[d];
    cnt = cnt < BCAP ? cnt : BCAP;
    int sv = (j < cnt) ? (int)bucket[(size_t)d * BCAP + j] : 0;
    float acc = 0.0f;
    int k = 0;
    for (; k + 4 <= cnt; k += 4) {
        int s0 = __shfl(sv, k, 64), s1 = __shfl(sv, k + 1, 64);
        int s2 = __shfl(sv, k + 2, 64), s3 = __shfl(sv, k + 3, 64);
        float v0 = bf2f(hs2b[(size_t)s0 * OUTC + j]);
        float v1 = bf2f(hs2b[(size_t)s1 * OUTC + j]);
        float v2 = bf2f(hs2b[(size_t)s2 * OUTC + j]);
        float v3 = bf2f(hs2b[(size_t)s3 * OUTC + j]);
        acc += (v0 + v1) + (v2 + v3);
    }
    for (; k < cnt; ++k) {
        int s = __shfl(sv, k, 64);
        acc += bf2f(hs2b[(size_t)s * OUTC + j]);
    }
    float dd = z4[d].w;
    out[(size_t)d * OUTC + j] = dd * (acc + bf2f(hs2b[(size_t)d * OUTC + j])) + b2[j];
}

__global__ void ovf2_kernel(const int* __restrict__ ovf, const int* __restrict__ ovf_cnt,
                            const unsigned short* __restrict__ hs2b, const float4* __restrict__ z4,
                            float* __restrict__ out) {
    int cnt = *ovf_cnt;
    cnt = cnt < OVF_CAP ? cnt : OVF_CAP;
    for (int t = threadIdx.x; t < cnt * OUTC; t += blockDim.x) {
        int o = t >> 6, j = t & 63;
        int s = ovf[2 * o], d = ovf[2 * o + 1];
        atomicAdd(&out[(size_t)d * OUTC + j], z4[d].w * bf2f(hs2b[(size_t)s * OUTC + j]));
    }
}

static inline size_t align256(size_t v) { return (v + 255) & ~(size_t)255; }

extern "C" void kernel_launch(void* const* d_in, const int* in_sizes, int n_in,
                              void* d_out, int out_size, void* d_ws, size_t ws_size,
                              hipStream_t stream) {
    const float* x  = (const float*)d_in[0];
    const int*   ei = (const int*)d_in[1];
    const float* W1 = (const float*)d_in[2];
    const float* b1 = (const float*)d_in[3];
    const float* W2 = (const float*)d_in[4];
    const float* b2 = (const float*)d_in[5];
    float* out = (float*)d_out;

    const int N = in_sizes[0] / INC;
    const int E = in_sizes[1] / 2;
    const int* src = ei;
    const int* dst = ei + E;
    const bool u16 = (N <= 65535);
    const int NCB = (N + 255) >> 8;

    char* ws = (char*)d_ws;
    size_t off = 0;
    int*    cursor  = (int*)(ws + off);    off += align256((size_t)N * 4);
    float4* z4      = (float4*)(ws + off); off += align256((size_t)N * 16);
    float4* agg4    = (float4*)(ws + off); off += align256((size_t)N * 16);
    int*    ovf_cnt = (int*)(ws + off);    off += 256;
    int*    ovf     = (int*)(ws + off);    off += (size_t)OVF_CAP * 8;
    int*    cboff   = (int*)(ws + off);    off += align256((size_t)NCBMAX * 4);
    int*    cbcnt   = (int*)(ws + off);    off += align256((size_t)NCBMAX * 4);
    int*    blockhist = (int*)(ws + off);  off += align256((size_t)NB1 * NCBMAX * 4);
    unsigned int* part = (unsigned int*)(ws + off); off += align256((size_t)E * 4);
    void*   bucket  = (void*)(ws + off);
    off += align256(u16 ? (size_t)NCB * 256 * BCAP * 2 : (size_t)N * BCAP * 4);
    unsigned short* hs2b = (unsigned short*)(ws + off); off += (size_t)N * OUTC * 2;

    const int B = 256;

    hipMemsetAsync(ovf_cnt, 0, 64, stream);

    if (u16) {
        int chunk = (E + NB1 - 1) / NB1;
        hist_kernel<<<NB1, B, 0, stream>>>(dst, E, chunk, NCB, blockhist);
        scanA_kernel<<<1, B, 0, stream>>>(blockhist, NB1, NCB, cboff, cbcnt);
        scanB_kernel<<<NCB, NB1, 0, stream>>>(blockhist, NCB, cboff);
        place_kernel<<<NB1, B, 0, stream>>>(src, dst, E, chunk, NCB, blockhist, part);
        bin_kernel<<<NCB, B, 0, stream>>>(part, cboff, cbcnt, x, N, cursor,
                                          (unsigned short*)bucket, z4, ovf, ovf_cnt);
    } else {
        hipMemsetAsync(cursor, 0, (size_t)N * sizeof(int), stream);
        int grid = (E + B * EPT - 1) / (B * EPT);
        int T = grid * B;
        fill_bucket_kernel<int><<<grid, B, 0, stream>>>(src, dst, E, T, cursor, (int*)bucket,
                                                        ovf, ovf_cnt);
        z4_kernel<<<(N + B - 1) / B, B, 0, stream>>>(x, cursor, z4, N);
    }

    // ---- layer 1 (3-dim gather aggregation, no atomics) ----
    if (u16)
        gather1_kernel<unsigned short><<<(N + 3) / 4, B, 0, stream>>>(
            cursor, (const unsigned short*)bucket, z4, agg4, N);
    else
        gather1_kernel<int><<<(N + 3) / 4, B, 0, stream>>>(
            cursor, (const int*)bucket, z4, agg4, N);
    ovf1_kernel<<<1, B, 0, stream>>>(ovf, ovf_cnt, z4, agg4);

    // ---- fused hidden (relu(u@W1+b1) @ W2, register-tiled GEMM, bf16 out) ----
    hidden_kernel<<<(N + NT - 1) / NT, 256, 0, stream>>>(agg4, z4, W1, b1, W2, hs2b, N);

    // ---- layer 2 gather ----
    if (u16)
        gather2_kernel<unsigned short><<<(N + 3) / 4, B, 0, stream>>>(
            cursor, (const unsigned short*)bucket, hs2b, z4, b2, out, N);
    else
        gather2_kernel<int><<<(N + 3) / 4, B, 0, stream>>>(
            cursor, (const int*)bucket, hs2b, z4, b2, out, N);
    ovf2_kernel<<<1, B, 0, stream>>>(ovf, ovf_cnt, hs2b, z4, out);
}

// Round 10
// 167.696 us; speedup vs baseline: 1.2247x; 1.0262x over previous
//
#include <hip/hip_runtime.h>
#include <hip/hip_bf16.h>

#define HID 128
#define OUTC 64
#define INC 3
#define BCAP 64        // bucket capacity per node (storage only; degree is exact)
#define OVF_CAP 8192   // overflow edge list capacity (expected usage: 0)
#define NT 64          // nodes per block in hidden GEMM
#define NCBMAX 256     // max coarse buckets (N<=65535 -> NCB<=256)
#define NB1 128        // blocks for hist/place passes
#define EPT 4          // legacy path

static __device__ __forceinline__ unsigned short f2bf(float f) {
    __hip_bfloat16 b = __float2bfloat16(f);
    return *reinterpret_cast<unsigned short*>(&b);
}
static __device__ __forceinline__ float bf2f(unsigned short u) {
    __hip_bfloat16 b = *reinterpret_cast<__hip_bfloat16*>(&u);
    return __bfloat162float(b);
}

// ================= two-level counting-sort bucket build (N <= 65535 path) =================
// [all proven in round 8]

__global__ void hist_kernel(const int* __restrict__ dst, int E, int chunk, int NCB,
                            int* __restrict__ blockhist) {
    __shared__ int hist[NCBMAX];
    int t = threadIdx.x;
    for (int i = t; i < NCBMAX; i += 256) hist[i] = 0;
    __syncthreads();
    int s0 = blockIdx.x * chunk;
    int s1 = min(E, s0 + chunk);
    for (int e = s0 + t; e < s1; e += 256) atomicAdd(&hist[dst[e] >> 8], 1);
    __syncthreads();
    for (int i = t; i < NCB; i += 256) blockhist[blockIdx.x * NCB + i] = hist[i];
}

__global__ void scanA_kernel(const int* __restrict__ blockhist, int NB, int NCB,
                             int* __restrict__ cboff, int* __restrict__ cbcnt) {
    __shared__ int v[NCBMAX];
    int t = threadIdx.x;
    int s = 0;
    if (t < NCB) {
#pragma unroll 8
        for (int b = 0; b < NB; ++b) s += blockhist[b * NCB + t];   // independent loads
    }
    v[t] = (t < NCB) ? s : 0;
    __syncthreads();
    for (int o = 1; o < NCBMAX; o <<= 1) {
        int add = (t >= o) ? v[t - o] : 0;
        __syncthreads();
        v[t] += add;
        __syncthreads();
    }
    if (t < NCB) { cboff[t] = v[t] - s; cbcnt[t] = s; }
}

__global__ void scanB_kernel(int* __restrict__ blockhist, int NCB,
                             const int* __restrict__ cboff) {
    __shared__ int v[NB1];
    int i = blockIdx.x;     // bucket
    int t = threadIdx.x;    // block index
    int c = blockhist[t * NCB + i];
    v[t] = c;
    __syncthreads();
    for (int o = 1; o < NB1; o <<= 1) {
        int add = (t >= o) ? v[t - o] : 0;
        __syncthreads();
        v[t] += add;
        __syncthreads();
    }
    blockhist[t * NCB + i] = cboff[i] + v[t] - c;
}

__global__ void place_kernel(const int* __restrict__ src, const int* __restrict__ dst, int E,
                             int chunk, int NCB, const int* __restrict__ blockhist,
                             unsigned int* __restrict__ part) {
    __shared__ int base[NCBMAX];
    __shared__ int lofs[NCBMAX];
    int t = threadIdx.x;
    for (int i = t; i < NCB; i += 256) { base[i] = blockhist[blockIdx.x * NCB + i]; lofs[i] = 0; }
    __syncthreads();
    int s0 = blockIdx.x * chunk;
    int s1 = min(E, s0 + chunk);
    for (int e = s0 + t; e < s1; e += 256) {
        int d = dst[e], s = src[e];
        int cb = d >> 8;
        int p = atomicAdd(&lofs[cb], 1);
        part[base[cb] + p] = (unsigned)s | ((unsigned)(d & 255) << 16);
    }
}

__global__ __launch_bounds__(256) void bin_kernel(const unsigned int* __restrict__ part,
                                                  const int* __restrict__ cboff,
                                                  const int* __restrict__ cbcnt,
                                                  const float* __restrict__ x, int N,
                                                  int* __restrict__ cursor,
                                                  unsigned short* __restrict__ bucket,
                                                  float4* __restrict__ z4,
                                                  int* __restrict__ ovf, int* __restrict__ ovf_cnt) {
    __shared__ int lcnt[256];
    __shared__ unsigned short lbuck[256 * BCAP];   // 32 KB
    int cb = blockIdx.x, t = threadIdx.x;
    lcnt[t] = 0;
    __syncthreads();
    int start = cboff[cb], cnt = cbcnt[cb];
    for (int i = t; i < cnt; i += 256) {
        unsigned pk = part[start + i];
        int s = pk & 0xFFFF;
        int ln = (pk >> 16) & 0xFF;
        int p = atomicAdd(&lcnt[ln], 1);
        if (p < BCAP) {
            lbuck[ln * BCAP + p] = (unsigned short)s;
        } else {
            int o = atomicAdd(ovf_cnt, 1);
            if (o < OVF_CAP) { ovf[2 * o] = s; ovf[2 * o + 1] = cb * 256 + ln; }
        }
    }
    __syncthreads();
    int d = cb * 256 + t;
    if (d < N) {
        int deg = lcnt[t];                         // exact degree (incl. >BCAP spill)
        cursor[d] = deg;
        float dd = rsqrtf((float)(deg + 1));       // +1 = self loop
        z4[d] = make_float4(dd * x[3 * d], dd * x[3 * d + 1], dd * x[3 * d + 2], dd);
    }
    const uint4* lsrc = (const uint4*)lbuck;
    uint4* gdst = (uint4*)(bucket + (size_t)cb * 256 * BCAP);
    for (int i = t; i < (256 * BCAP * 2) / 16; i += 256) gdst[i] = lsrc[i];  // dense copy
}

// ================= legacy path (N > 65535): atomic fill + z4 =================

template <typename IT>
__global__ void fill_bucket_kernel(const int* __restrict__ src, const int* __restrict__ dst, int E,
                                   int T, int* __restrict__ cursor, IT* __restrict__ bucket,
                                   int* __restrict__ ovf, int* __restrict__ ovf_cnt) {
    int tid = blockIdx.x * blockDim.x + threadIdx.x;
    int d[EPT], s[EPT], p[EPT];
    bool v[EPT];
#pragma unroll
    for (int k = 0; k < EPT; ++k) {
        int e = tid + k * T;
        v[k] = (e < E);
        d[k] = v[k] ? dst[e] : 0;
        s[k] = v[k] ? src[e] : 0;
    }
#pragma unroll
    for (int k = 0; k < EPT; ++k)
        if (v[k]) p[k] = atomicAdd(&cursor[d[k]], 1);
#pragma unroll
    for (int k = 0; k < EPT; ++k) {
        if (v[k]) {
            if (p[k] < BCAP) {
                bucket[(size_t)d[k] * BCAP + p[k]] = (IT)s[k];
            } else {
                int o = atomicAdd(ovf_cnt, 1);
                if (o < OVF_CAP) { ovf[2 * o] = s[k]; ovf[2 * o + 1] = d[k]; }
            }
        }
    }
}

__global__ void z4_kernel(const float* __restrict__ x, const int* __restrict__ cursor,
                          float4* __restrict__ z4, int N) {
    int i = blockIdx.x * blockDim.x + threadIdx.x;
    if (i < N) {
        float dd = rsqrtf((float)(cursor[i] + 1));
        z4[i] = make_float4(dd * x[3 * i], dd * x[3 * i + 1], dd * x[3 * i + 2], dd);
    }
}

// ================= layer-1 aggregation: agg4[d] = sum z4[s].xyz   [round-8 proven] ==========

template <typename IT>
__global__ void gather1_kernel(const int* __restrict__ cursor, const IT* __restrict__ bucket,
                               const float4* __restrict__ z4, float4* __restrict__ agg4, int N) {
    int wid = threadIdx.x >> 6;
    int j = threadIdx.x & 63;
    int d = blockIdx.x * 4 + wid;
    if (d >= N) return;
    int cnt = cursor[d];
    cnt = cnt < BCAP ? cnt : BCAP;
    float a0 = 0.f, a1 = 0.f, a2 = 0.f;
    if (j < cnt) {
        int s = (int)bucket[(size_t)d * BCAP + j];
        float4 zv = z4[s];
        a0 = zv.x; a1 = zv.y; a2 = zv.z;
    }
#pragma unroll
    for (int o = 32; o > 0; o >>= 1) {
        a0 += __shfl_xor(a0, o, 64);
        a1 += __shfl_xor(a1, o, 64);
        a2 += __shfl_xor(a2, o, 64);
    }
    if (j == 0) agg4[d] = make_float4(a0, a1, a2, 0.f);
}

__global__ void ovf1_kernel(const int* __restrict__ ovf, const int* __restrict__ ovf_cnt,
                            const float4* __restrict__ z4, float4* __restrict__ agg4) {
    int cnt = *ovf_cnt;
    cnt = cnt < OVF_CAP ? cnt : OVF_CAP;
    for (int t = threadIdx.x; t < cnt; t += blockDim.x) {
        int s = ovf[2 * t], d = ovf[2 * t + 1];
        float4 zv = z4[s];
        float* a = (float*)&agg4[d];
        atomicAdd(a + 0, zv.x);
        atomicAdd(a + 1, zv.y);
        atomicAdd(a + 2, zv.z);
    }
}

// ============ fused hidden GEMM: u -> relu(u@W1+b1) -> hs2 = dinv*(h@W2), bf16 out ============

__global__ __launch_bounds__(256) void hidden_kernel(const float4* __restrict__ agg4,
                                                     const float4* __restrict__ z4,
                                                     const float* __restrict__ W1,
                                                     const float* __restrict__ b1,
                                                     const float* __restrict__ W2,
                                                     unsigned short* __restrict__ hs2b, int N) {
    __shared__ float h_s[HID][NT];       // 32 KB, k-major
    __shared__ float w_s[HID * OUTC];    // 32 KB
    int t = threadIdx.x;
    int base = blockIdx.x * NT;

    for (int i = t; i < HID * OUTC; i += 256) w_s[i] = W2[i];

    {
        int n = t & 63;
        int d = base + n;
        float u0 = 0.f, u1 = 0.f, u2 = 0.f;
        if (d < N) {
            float4 zv = z4[d];
            float4 av = agg4[d];
            float dd = zv.w;
            u0 = dd * (av.x + zv.x);
            u1 = dd * (av.y + zv.y);
            u2 = dd * (av.z + zv.z);
        }
        int k0 = t >> 6;
#pragma unroll
        for (int i = 0; i < HID / 4; ++i) {
            int k = k0 + 4 * i;
            float v = u0 * W1[k] + u1 * W1[HID + k] + u2 * W1[2 * HID + k] + b1[k];
            h_s[k][n] = fmaxf(v, 0.f);
        }
    }
    __syncthreads();

    int tx = t & 15, ty = t >> 4;
    float acc[4][4] = {};
#pragma unroll 8
    for (int k = 0; k < HID; ++k) {
        float4 hv = *(const float4*)&h_s[k][ty * 4];
        float4 wv = *(const float4*)&w_s[k * OUTC + tx * 4];
        float hr[4] = {hv.x, hv.y, hv.z, hv.w};
        float wr[4] = {wv.x, wv.y, wv.z, wv.w};
#pragma unroll
        for (int r = 0; r < 4; ++r)
#pragma unroll
            for (int c = 0; c < 4; ++c) acc[r][c] = fmaf(hr[r], wr[c], acc[r][c]);
    }

#pragma unroll
    for (int r = 0; r < 4; ++r) {
        int n = ty * 4 + r;
        int d = base + n;
        if (d < N) {
            float dd = z4[d].w;
            ushort4 o;
            o.x = f2bf(dd * acc[r][0]);
            o.y = f2bf(dd * acc[r][1]);
            o.z = f2bf(dd * acc[r][2]);
            o.w = f2bf(dd * acc[r][3]);
            *(ushort4*)&hs2b[(size_t)d * OUTC + tx * 4] = o;
        }
    }
}

// ============ layer-2 gather: out[d] = dinv[d]*(sum hs2[s] + hs2[d]) + b2 ============
// [round-8 proven structure; added an 8-deep unroll tier above the proven 4-deep one]

template <typename IT>
__global__ void gather2_kernel(const int* __restrict__ cursor, const IT* __restrict__ bucket,
                               const unsigned short* __restrict__ hs2b, const float4* __restrict__ z4,
                               const float* __restrict__ b2, float* __restrict__ out, int N) {
    int wid = threadIdx.x >> 6;
    int j = threadIdx.x & 63;
    int d = blockIdx.x * 4 + wid;
    if (d >= N) return;
    int cnt = cursor[d];
    cnt = cnt < BCAP ? cnt : BCAP;
    int sv = (j < cnt) ? (int)bucket[(size_t)d * BCAP + j] : 0;
    float acc = 0.0f;
    int k = 0;
    for (; k + 8 <= cnt; k += 8) {                    // 8 independent row loads in flight
        int s0 = __shfl(sv, k, 64),     s1 = __shfl(sv, k + 1, 64);
        int s2 = __shfl(sv, k + 2, 64), s3 = __shfl(sv, k + 3, 64);
        int s4 = __shfl(sv, k + 4, 64), s5 = __shfl(sv, k + 5, 64);
        int s6 = __shfl(sv, k + 6, 64), s7 = __shfl(sv, k + 7, 64);
        float v0 = bf2f(hs2b[(size_t)s0 * OUTC + j]);
        float v1 = bf2f(hs2b[(size_t)s1 * OUTC + j]);
        float v2 = bf2f(hs2b[(size_t)s2 * OUTC + j]);
        float v3 = bf2f(hs2b[(size_t)s3 * OUTC + j]);
        float v4 = bf2f(hs2b[(size_t)s4 * OUTC + j]);
        float v5 = bf2f(hs2b[(size_t)s5 * OUTC + j]);
        float v6 = bf2f(hs2b[(size_t)s6 * OUTC + j]);
        float v7 = bf2f(hs2b[(size_t)s7 * OUTC + j]);
        acc += ((v0 + v1) + (v2 + v3)) + ((v4 + v5) + (v6 + v7));
    }
    for (; k + 4 <= cnt; k += 4) {
        int s0 = __shfl(sv, k, 64), s1 = __shfl(sv, k + 1, 64);
        int s2 = __shfl(sv, k + 2, 64), s3 = __shfl(sv, k + 3, 64);
        float v0 = bf2f(hs2b[(size_t)s0 * OUTC + j]);
        float v1 = bf2f(hs2b[(size_t)s1 * OUTC + j]);
        float v2 = bf2f(hs2b[(size_t)s2 * OUTC + j]);
        float v3 = bf2f(hs2b[(size_t)s3 * OUTC + j]);
        acc += (v0 + v1) + (v2 + v3);
    }
    for (; k < cnt; ++k) {
        int s = __shfl(sv, k, 64);
        acc += bf2f(hs2b[(size_t)s * OUTC + j]);
    }
    float dd = z4[d].w;
    out[(size_t)d * OUTC + j] = dd * (acc + bf2f(hs2b[(size_t)d * OUTC + j])) + b2[j];
}

__global__ void ovf2_kernel(const int* __restrict__ ovf, const int* __restrict__ ovf_cnt,
                            const unsigned short* __restrict__ hs2b, const float4* __restrict__ z4,
                            float* __restrict__ out) {
    int cnt = *ovf_cnt;
    cnt = cnt < OVF_CAP ? cnt : OVF_CAP;
    for (int t = threadIdx.x; t < cnt * OUTC; t += blockDim.x) {
        int o = t >> 6, j = t & 63;
        int s = ovf[2 * o], d = ovf[2 * o + 1];
        atomicAdd(&out[(size_t)d * OUTC + j], z4[d].w * bf2f(hs2b[(size_t)s * OUTC + j]));
    }
}

static inline size_t align256(size_t v) { return (v + 255) & ~(size_t)255; }

extern "C" void kernel_launch(void* const* d_in, const int* in_sizes, int n_in,
                              void* d_out, int out_size, void* d_ws, size_t ws_size,
                              hipStream_t stream) {
    const float* x  = (const float*)d_in[0];
    const int*   ei = (const int*)d_in[1];
    const float* W1 = (const float*)d_in[2];
    const float* b1 = (const float*)d_in[3];
    const float* W2 = (const float*)d_in[4];
    const float* b2 = (const float*)d_in[5];
    float* out = (float*)d_out;

    const int N = in_sizes[0] / INC;
    const int E = in_sizes[1] / 2;
    const int* src = ei;
    const int* dst = ei + E;
    const bool u16 = (N <= 65535);
    const int NCB = (N + 255) >> 8;

    char* ws = (char*)d_ws;
    size_t off = 0;
    int*    cursor  = (int*)(ws + off);    off += align256((size_t)N * 4);
    float4* z4      = (float4*)(ws + off); off += align256((size_t)N * 16);
    float4* agg4    = (float4*)(ws + off); off += align256((size_t)N * 16);
    int*    ovf_cnt = (int*)(ws + off);    off += 256;
    int*    ovf     = (int*)(ws + off);    off += (size_t)OVF_CAP * 8;
    int*    cboff   = (int*)(ws + off);    off += align256((size_t)NCBMAX * 4);
    int*    cbcnt   = (int*)(ws + off);    off += align256((size_t)NCBMAX * 4);
    int*    blockhist = (int*)(ws + off);  off += align256((size_t)NB1 * NCBMAX * 4);
    unsigned int* part = (unsigned int*)(ws + off); off += align256((size_t)E * 4);
    void*   bucket  = (void*)(ws + off);
    off += align256(u16 ? (size_t)NCB * 256 * BCAP * 2 : (size_t)N * BCAP * 4);
    unsigned short* hs2b = (unsigned short*)(ws + off); off += (size_t)N * OUTC * 2;

    const int B = 256;

    hipMemsetAsync(ovf_cnt, 0, 64, stream);

    if (u16) {
        int chunk = (E + NB1 - 1) / NB1;
        hist_kernel<<<NB1, B, 0, stream>>>(dst, E, chunk, NCB, blockhist);
        scanA_kernel<<<1, B, 0, stream>>>(blockhist, NB1, NCB, cboff, cbcnt);
        scanB_kernel<<<NCB, NB1, 0, stream>>>(blockhist, NCB, cboff);
        place_kernel<<<NB1, B, 0, stream>>>(src, dst, E, chunk, NCB, blockhist, part);
        bin_kernel<<<NCB, B, 0, stream>>>(part, cboff, cbcnt, x, N, cursor,
                                          (unsigned short*)bucket, z4, ovf, ovf_cnt);
    } else {
        hipMemsetAsync(cursor, 0, (size_t)N * sizeof(int), stream);
        int grid = (E + B * EPT - 1) / (B * EPT);
        int T = grid * B;
        fill_bucket_kernel<int><<<grid, B, 0, stream>>>(src, dst, E, T, cursor, (int*)bucket,
                                                        ovf, ovf_cnt);
        z4_kernel<<<(N + B - 1) / B, B, 0, stream>>>(x, cursor, z4, N);
    }

    // ---- layer 1 (3-dim gather aggregation, no atomics) ----
    if (u16)
        gather1_kernel<unsigned short><<<(N + 3) / 4, B, 0, stream>>>(
            cursor, (const unsigned short*)bucket, z4, agg4, N);
    else
        gather1_kernel<int><<<(N + 3) / 4, B, 0, stream>>>(
            cursor, (const int*)bucket, z4, agg4, N);
    ovf1_kernel<<<1, B, 0, stream>>>(ovf, ovf_cnt, z4, agg4);

    // ---- fused hidden (relu(u@W1+b1) @ W2, register-tiled GEMM, bf16 out) ----
    hidden_kernel<<<(N + NT - 1) / NT, 256, 0, stream>>>(agg4, z4, W1, b1, W2, hs2b, N);

    // ---- layer 2 gather ----
    if (u16)
        gather2_kernel<unsigned short><<<(N + 3) / 4, B, 0, stream>>>(
            cursor, (const unsigned short*)bucket, hs2b, z4, b2, out, N);
    else
        gather2_kernel<int><<<(N + 3) / 4, B, 0, stream>>>(
            cursor, (const int*)bucket, hs2b, z4, b2, out, N);
    ovf2_kernel<<<1, B, 0, stream>>>(ovf, ovf_cnt, hs2b, z4, out);
}

// Round 11
// 153.979 us; speedup vs baseline: 1.3339x; 1.0891x over previous
//
#include <hip/hip_runtime.h>
#include <hip/hip_bf16.h>

#define HID 128
#define OUTC 64
#define INC 3
#define BCAP 64        // bucket capacity per node (storage only; degree is exact)
#define OVF_CAP 8192   // overflow edge list capacity (expected usage: 0)
#define NT 64          // nodes per block in hidden GEMM
#define NCBMAX 256     // max coarse buckets (N<=65535 -> NCB<=256)
#define CAP8K 8192     // slots per coarse bucket in part[] (mean 4082, 64 sigma headroom)
#define KPT 8          // edges per thread in place2
#define EPT 4          // legacy path

static __device__ __forceinline__ unsigned short f2bf(float f) {
    __hip_bfloat16 b = __float2bfloat16(f);
    return *reinterpret_cast<unsigned short*>(&b);
}
static __device__ __forceinline__ float bf2f(unsigned short u) {
    __hip_bfloat16 b = *reinterpret_cast<__hip_bfloat16*>(&u);
    return __bfloat162float(b);
}

// ================= capacity-based counting-sort bucket build (N <= 65535 path) =================
// place2: register-staged edges, LDS pre-count, one global atomic per (block,bucket) reserve.
// part[] has a fixed CAP8K region per coarse bucket; spill -> exact ovf path (0 in practice).

__global__ __launch_bounds__(256) void place2_kernel(const int* __restrict__ src,
                                                     const int* __restrict__ dst, int E, int NCB,
                                                     int* __restrict__ cbcur,
                                                     unsigned int* __restrict__ part,
                                                     int* __restrict__ ovf, int* __restrict__ ovf_cnt) {
    __shared__ int lhist[NCBMAX];
    __shared__ int lbase[NCBMAX];
    int t = threadIdx.x;
    int s0 = blockIdx.x * (256 * KPT);
    for (int i = t; i < NCBMAX; i += 256) lhist[i] = 0;
    __syncthreads();

    unsigned pk[KPT];
    int cbv[KPT];
    bool val[KPT];
#pragma unroll
    for (int i = 0; i < KPT; ++i) {
        int e = s0 + t + i * 256;                 // coalesced
        val[i] = (e < E);
        if (val[i]) {
            int d = dst[e], s = src[e];
            cbv[i] = d >> 8;
            pk[i] = (unsigned)s | ((unsigned)(d & 255) << 16);
            atomicAdd(&lhist[cbv[i]], 1);
        }
    }
    __syncthreads();
    for (int i = t; i < NCB; i += 256) {
        int c = lhist[i];
        lbase[i] = c ? atomicAdd(&cbcur[i], c) : 0;   // reserve contiguous range
        lhist[i] = 0;                                  // reuse as local offset
    }
    __syncthreads();
#pragma unroll
    for (int i = 0; i < KPT; ++i) {
        if (val[i]) {
            int cb = cbv[i];
            int p = atomicAdd(&lhist[cb], 1);
            int slot = lbase[cb] + p;
            if (slot < CAP8K) {
                part[(size_t)cb * CAP8K + slot] = pk[i];
            } else {                                   // impossible in practice; exact fallback
                int o = atomicAdd(ovf_cnt, 1);
                if (o < OVF_CAP) {
                    ovf[2 * o] = (int)(pk[i] & 0xFFFF);
                    ovf[2 * o + 1] = cb * 256 + (int)((pk[i] >> 16) & 0xFF);
                }
            }
        }
    }
}

// bin: one block per coarse bucket — LDS binning, dense 32KB bucket write;
// fuses exact degree -> cursor and z4 = (dinv*x, dinv)   [proven structure]
__global__ __launch_bounds__(256) void bin_kernel(const unsigned int* __restrict__ part,
                                                  const int* __restrict__ cbcur,
                                                  const float* __restrict__ x, int N,
                                                  int* __restrict__ cursor,
                                                  unsigned short* __restrict__ bucket,
                                                  float4* __restrict__ z4,
                                                  int* __restrict__ ovf, int* __restrict__ ovf_cnt) {
    __shared__ int lcnt[256];
    __shared__ unsigned short lbuck[256 * BCAP];   // 32 KB
    int cb = blockIdx.x, t = threadIdx.x;
    lcnt[t] = 0;
    __syncthreads();
    int cnt = cbcur[cb];
    cnt = cnt < CAP8K ? cnt : CAP8K;
    size_t start = (size_t)cb * CAP8K;
    for (int i = t; i < cnt; i += 256) {
        unsigned pk = part[start + i];
        int s = pk & 0xFFFF;
        int ln = (pk >> 16) & 0xFF;
        int p = atomicAdd(&lcnt[ln], 1);
        if (p < BCAP) {
            lbuck[ln * BCAP + p] = (unsigned short)s;
        } else {
            int o = atomicAdd(ovf_cnt, 1);
            if (o < OVF_CAP) { ovf[2 * o] = s; ovf[2 * o + 1] = cb * 256 + ln; }
        }
    }
    __syncthreads();
    int d = cb * 256 + t;
    if (d < N) {
        int deg = lcnt[t];                         // exact degree (incl. >BCAP spill)
        cursor[d] = deg;
        float dd = rsqrtf((float)(deg + 1));       // +1 = self loop
        z4[d] = make_float4(dd * x[3 * d], dd * x[3 * d + 1], dd * x[3 * d + 2], dd);
    }
    const uint4* lsrc = (const uint4*)lbuck;
    uint4* gdst = (uint4*)(bucket + (size_t)cb * 256 * BCAP);
    for (int i = t; i < (256 * BCAP * 2) / 16; i += 256) gdst[i] = lsrc[i];  // dense copy
}

// ================= legacy path (N > 65535): atomic fill + z4 =================

template <typename IT>
__global__ void fill_bucket_kernel(const int* __restrict__ src, const int* __restrict__ dst, int E,
                                   int T, int* __restrict__ cursor, IT* __restrict__ bucket,
                                   int* __restrict__ ovf, int* __restrict__ ovf_cnt) {
    int tid = blockIdx.x * blockDim.x + threadIdx.x;
    int d[EPT], s[EPT], p[EPT];
    bool v[EPT];
#pragma unroll
    for (int k = 0; k < EPT; ++k) {
        int e = tid + k * T;
        v[k] = (e < E);
        d[k] = v[k] ? dst[e] : 0;
        s[k] = v[k] ? src[e] : 0;
    }
#pragma unroll
    for (int k = 0; k < EPT; ++k)
        if (v[k]) p[k] = atomicAdd(&cursor[d[k]], 1);
#pragma unroll
    for (int k = 0; k < EPT; ++k) {
        if (v[k]) {
            if (p[k] < BCAP) {
                bucket[(size_t)d[k] * BCAP + p[k]] = (IT)s[k];
            } else {
                int o = atomicAdd(ovf_cnt, 1);
                if (o < OVF_CAP) { ovf[2 * o] = s[k]; ovf[2 * o + 1] = d[k]; }
            }
        }
    }
}

__global__ void z4_kernel(const float* __restrict__ x, const int* __restrict__ cursor,
                          float4* __restrict__ z4, int N) {
    int i = blockIdx.x * blockDim.x + threadIdx.x;
    if (i < N) {
        float dd = rsqrtf((float)(cursor[i] + 1));
        z4[i] = make_float4(dd * x[3 * i], dd * x[3 * i + 1], dd * x[3 * i + 2], dd);
    }
}

// ================= layer-1 aggregation: agg4[d] = sum z4[s].xyz   [proven] ==========

template <typename IT>
__global__ void gather1_kernel(const int* __restrict__ cursor, const IT* __restrict__ bucket,
                               const float4* __restrict__ z4, float4* __restrict__ agg4, int N) {
    int wid = threadIdx.x >> 6;
    int j = threadIdx.x & 63;
    int d = blockIdx.x * 4 + wid;
    if (d >= N) return;
    int cnt = cursor[d];
    cnt = cnt < BCAP ? cnt : BCAP;
    float a0 = 0.f, a1 = 0.f, a2 = 0.f;
    if (j < cnt) {
        int s = (int)bucket[(size_t)d * BCAP + j];
        float4 zv = z4[s];
        a0 = zv.x; a1 = zv.y; a2 = zv.z;
    }
#pragma unroll
    for (int o = 32; o > 0; o >>= 1) {
        a0 += __shfl_xor(a0, o, 64);
        a1 += __shfl_xor(a1, o, 64);
        a2 += __shfl_xor(a2, o, 64);
    }
    if (j == 0) agg4[d] = make_float4(a0, a1, a2, 0.f);
}

__global__ void ovf1_kernel(const int* __restrict__ ovf, const int* __restrict__ ovf_cnt,
                            const float4* __restrict__ z4, float4* __restrict__ agg4) {
    int cnt = *ovf_cnt;
    cnt = cnt < OVF_CAP ? cnt : OVF_CAP;
    for (int t = threadIdx.x; t < cnt; t += blockDim.x) {
        int s = ovf[2 * t], d = ovf[2 * t + 1];
        float4 zv = z4[s];
        float* a = (float*)&agg4[d];
        atomicAdd(a + 0, zv.x);
        atomicAdd(a + 1, zv.y);
        atomicAdd(a + 2, zv.z);
    }
}

// ============ fused hidden GEMM: u -> relu(u@W1+b1) -> hs2 = dinv*(h@W2), bf16 out ============

__global__ __launch_bounds__(256) void hidden_kernel(const float4* __restrict__ agg4,
                                                     const float4* __restrict__ z4,
                                                     const float* __restrict__ W1,
                                                     const float* __restrict__ b1,
                                                     const float* __restrict__ W2,
                                                     unsigned short* __restrict__ hs2b, int N) {
    __shared__ float h_s[HID][NT];       // 32 KB, k-major
    __shared__ float w_s[HID * OUTC];    // 32 KB
    int t = threadIdx.x;
    int base = blockIdx.x * NT;

    for (int i = t; i < HID * OUTC; i += 256) w_s[i] = W2[i];

    {
        int n = t & 63;
        int d = base + n;
        float u0 = 0.f, u1 = 0.f, u2 = 0.f;
        if (d < N) {
            float4 zv = z4[d];
            float4 av = agg4[d];
            float dd = zv.w;
            u0 = dd * (av.x + zv.x);
            u1 = dd * (av.y + zv.y);
            u2 = dd * (av.z + zv.z);
        }
        int k0 = t >> 6;
#pragma unroll
        for (int i = 0; i < HID / 4; ++i) {
            int k = k0 + 4 * i;
            float v = u0 * W1[k] + u1 * W1[HID + k] + u2 * W1[2 * HID + k] + b1[k];
            h_s[k][n] = fmaxf(v, 0.f);
        }
    }
    __syncthreads();

    int tx = t & 15, ty = t >> 4;
    float acc[4][4] = {};
#pragma unroll 8
    for (int k = 0; k < HID; ++k) {
        float4 hv = *(const float4*)&h_s[k][ty * 4];
        float4 wv = *(const float4*)&w_s[k * OUTC + tx * 4];
        float hr[4] = {hv.x, hv.y, hv.z, hv.w};
        float wr[4] = {wv.x, wv.y, wv.z, wv.w};
#pragma unroll
        for (int r = 0; r < 4; ++r)
#pragma unroll
            for (int c = 0; c < 4; ++c) acc[r][c] = fmaf(hr[r], wr[c], acc[r][c]);
    }

#pragma unroll
    for (int r = 0; r < 4; ++r) {
        int n = ty * 4 + r;
        int d = base + n;
        if (d < N) {
            float dd = z4[d].w;
            ushort4 o;
            o.x = f2bf(dd * acc[r][0]);
            o.y = f2bf(dd * acc[r][1]);
            o.z = f2bf(dd * acc[r][2]);
            o.w = f2bf(dd * acc[r][3]);
            *(ushort4*)&hs2b[(size_t)d * OUTC + tx * 4] = o;
        }
    }
}

// ============ layer-2 gather: out[d] = dinv[d]*(sum hs2[s] + hs2[d]) + b2   [proven] ==========

template <typename IT>
__global__ void gather2_kernel(const int* __restrict__ cursor, const IT* __restrict__ bucket,
                               const unsigned short* __restrict__ hs2b, const float4* __restrict__ z4,
                               const float* __restrict__ b2, float* __restrict__ out, int N) {
    int wid = threadIdx.x >> 6;
    int j = threadIdx.x & 63;
    int d = blockIdx.x * 4 + wid;
    if (d >= N) return;
    int cnt = cursor[d];
    cnt = cnt < BCAP ? cnt : BCAP;
    int sv = (j < cnt) ? (int)bucket[(size_t)d * BCAP + j] : 0;
    float acc = 0.0f;
    int k = 0;
    for (; k + 8 <= cnt; k += 8) {                    // 8 independent row loads in flight
        int s0 = __shfl(sv, k, 64),     s1 = __shfl(sv, k + 1, 64);
        int s2 = __shfl(sv, k + 2, 64), s3 = __shfl(sv, k + 3, 64);
        int s4 = __shfl(sv, k + 4, 64), s5 = __shfl(sv, k + 5, 64);
        int s6 = __shfl(sv, k + 6, 64), s7 = __shfl(sv, k + 7, 64);
        float v0 = bf2f(hs2b[(size_t)s0 * OUTC + j]);
        float v1 = bf2f(hs2b[(size_t)s1 * OUTC + j]);
        float v2 = bf2f(hs2b[(size_t)s2 * OUTC + j]);
        float v3 = bf2f(hs2b[(size_t)s3 * OUTC + j]);
        float v4 = bf2f(hs2b[(size_t)s4 * OUTC + j]);
        float v5 = bf2f(hs2b[(size_t)s5 * OUTC + j]);
        float v6 = bf2f(hs2b[(size_t)s6 * OUTC + j]);
        float v7 = bf2f(hs2b[(size_t)s7 * OUTC + j]);
        acc += ((v0 + v1) + (v2 + v3)) + ((v4 + v5) + (v6 + v7));
    }
    for (; k + 4 <= cnt; k += 4) {
        int s0 = __shfl(sv, k, 64), s1 = __shfl(sv, k + 1, 64);
        int s2 = __shfl(sv, k + 2, 64), s3 = __shfl(sv, k + 3, 64);
        float v0 = bf2f(hs2b[(size_t)s0 * OUTC + j]);
        float v1 = bf2f(hs2b[(size_t)s1 * OUTC + j]);
        float v2 = bf2f(hs2b[(size_t)s2 * OUTC + j]);
        float v3 = bf2f(hs2b[(size_t)s3 * OUTC + j]);
        acc += (v0 + v1) + (v2 + v3);
    }
    for (; k < cnt; ++k) {
        int s = __shfl(sv, k, 64);
        acc += bf2f(hs2b[(size_t)s * OUTC + j]);
    }
    float dd = z4[d].w;
    out[(size_t)d * OUTC + j] = dd * (acc + bf2f(hs2b[(size_t)d * OUTC + j])) + b2[j];
}

__global__ void ovf2_kernel(const int* __restrict__ ovf, const int* __restrict__ ovf_cnt,
                            const unsigned short* __restrict__ hs2b, const float4* __restrict__ z4,
                            float* __restrict__ out) {
    int cnt = *ovf_cnt;
    cnt = cnt < OVF_CAP ? cnt : OVF_CAP;
    for (int t = threadIdx.x; t < cnt * OUTC; t += blockDim.x) {
        int o = t >> 6, j = t & 63;
        int s = ovf[2 * o], d = ovf[2 * o + 1];
        atomicAdd(&out[(size_t)d * OUTC + j], z4[d].w * bf2f(hs2b[(size_t)s * OUTC + j]));
    }
}

static inline size_t align256(size_t v) { return (v + 255) & ~(size_t)255; }

extern "C" void kernel_launch(void* const* d_in, const int* in_sizes, int n_in,
                              void* d_out, int out_size, void* d_ws, size_t ws_size,
                              hipStream_t stream) {
    const float* x  = (const float*)d_in[0];
    const int*   ei = (const int*)d_in[1];
    const float* W1 = (const float*)d_in[2];
    const float* b1 = (const float*)d_in[3];
    const float* W2 = (const float*)d_in[4];
    const float* b2 = (const float*)d_in[5];
    float* out = (float*)d_out;

    const int N = in_sizes[0] / INC;
    const int E = in_sizes[1] / 2;
    const int* src = ei;
    const int* dst = ei + E;
    const bool u16 = (N <= 65535);
    const int NCB = (N + 255) >> 8;

    char* ws = (char*)d_ws;
    size_t off = 0;
    int*    cursor  = (int*)(ws + off);    off += align256((size_t)N * 4);
    float4* z4      = (float4*)(ws + off); off += align256((size_t)N * 16);
    float4* agg4    = (float4*)(ws + off); off += align256((size_t)N * 16);
    int*    cbcur   = (int*)(ws + off);    off += (size_t)NCBMAX * 4;      // zeroed with ovf_cnt
    int*    ovf_cnt = (int*)(ws + off);    off += 256;
    int*    ovf     = (int*)(ws + off);    off += (size_t)OVF_CAP * 8;
    unsigned int* part = (unsigned int*)(ws + off);
    off += align256(u16 ? (size_t)NCB * CAP8K * 4 : 0);
    void*   bucket  = (void*)(ws + off);
    off += align256(u16 ? (size_t)NCB * 256 * BCAP * 2 : (size_t)N * BCAP * 4);
    unsigned short* hs2b = (unsigned short*)(ws + off); off += (size_t)N * OUTC * 2;

    const int B = 256;

    if (u16) {
        hipMemsetAsync(cbcur, 0, (size_t)NCBMAX * 4 + 256, stream);        // cbcur + ovf_cnt
        int NB = (E + 256 * KPT - 1) / (256 * KPT);
        place2_kernel<<<NB, B, 0, stream>>>(src, dst, E, NCB, cbcur, part, ovf, ovf_cnt);
        bin_kernel<<<NCB, B, 0, stream>>>(part, cbcur, x, N, cursor,
                                          (unsigned short*)bucket, z4, ovf, ovf_cnt);
    } else {
        hipMemsetAsync(cursor, 0, (size_t)N * sizeof(int), stream);
        hipMemsetAsync(ovf_cnt, 0, 64, stream);
        int grid = (E + B * EPT - 1) / (B * EPT);
        int T = grid * B;
        fill_bucket_kernel<int><<<grid, B, 0, stream>>>(src, dst, E, T, cursor, (int*)bucket,
                                                        ovf, ovf_cnt);
        z4_kernel<<<(N + B - 1) / B, B, 0, stream>>>(x, cursor, z4, N);
    }

    // ---- layer 1 (3-dim gather aggregation, no atomics) ----
    if (u16)
        gather1_kernel<unsigned short><<<(N + 3) / 4, B, 0, stream>>>(
            cursor, (const unsigned short*)bucket, z4, agg4, N);
    else
        gather1_kernel<int><<<(N + 3) / 4, B, 0, stream>>>(
            cursor, (const int*)bucket, z4, agg4, N);
    ovf1_kernel<<<1, B, 0, stream>>>(ovf, ovf_cnt, z4, agg4);

    // ---- fused hidden (relu(u@W1+b1) @ W2, register-tiled GEMM, bf16 out) ----
    hidden_kernel<<<(N + NT - 1) / NT, 256, 0, stream>>>(agg4, z4, W1, b1, W2, hs2b, N);

    // ---- layer 2 gather ----
    if (u16)
        gather2_kernel<unsigned short><<<(N + 3) / 4, B, 0, stream>>>(
            cursor, (const unsigned short*)bucket, hs2b, z4, b2, out, N);
    else
        gather2_kernel<int><<<(N + 3) / 4, B, 0, stream>>>(
            cursor, (const int*)bucket, hs2b, z4, b2, out, N);
    ovf2_kernel<<<1, B, 0, stream>>>(ovf, ovf_cnt, hs2b, z4, out);
}

// Round 12
// 148.216 us; speedup vs baseline: 1.3857x; 1.0389x over previous
//
#include <hip/hip_runtime.h>
#include <hip/hip_bf16.h>

#define HID 128
#define OUTC 64
#define INC 3
#define BCAP 64        // bucket capacity per node (storage only; degree is exact)
#define OVF_CAP 8192   // overflow edge list capacity (expected usage: 0)
#define NT 64          // nodes per block in hidden GEMM
#define NCBMAX 256     // max coarse buckets (N<=65535 -> NCB<=256)
#define CAP8K 8192     // slots per coarse bucket in part[] (mean 4082, 64 sigma headroom)
#define KPT 8          // edges per thread in place2
#define EPT 4          // legacy path

static __device__ __forceinline__ unsigned short f2bf(float f) {
    __hip_bfloat16 b = __float2bfloat16(f);
    return *reinterpret_cast<unsigned short*>(&b);
}
static __device__ __forceinline__ float bf2f(unsigned short u) {
    __hip_bfloat16 b = *reinterpret_cast<__hip_bfloat16*>(&u);
    return __bfloat162float(b);
}

// ================= capacity-based counting-sort bucket build (N <= 65535 path) =================
// [proven round 11]

__global__ __launch_bounds__(256) void place2_kernel(const int* __restrict__ src,
                                                     const int* __restrict__ dst, int E, int NCB,
                                                     int* __restrict__ cbcur,
                                                     unsigned int* __restrict__ part,
                                                     int* __restrict__ ovf, int* __restrict__ ovf_cnt) {
    __shared__ int lhist[NCBMAX];
    __shared__ int lbase[NCBMAX];
    int t = threadIdx.x;
    int s0 = blockIdx.x * (256 * KPT);
    for (int i = t; i < NCBMAX; i += 256) lhist[i] = 0;
    __syncthreads();

    unsigned pk[KPT];
    int cbv[KPT];
    bool val[KPT];
#pragma unroll
    for (int i = 0; i < KPT; ++i) {
        int e = s0 + t + i * 256;                 // coalesced
        val[i] = (e < E);
        if (val[i]) {
            int d = dst[e], s = src[e];
            cbv[i] = d >> 8;
            pk[i] = (unsigned)s | ((unsigned)(d & 255) << 16);
            atomicAdd(&lhist[cbv[i]], 1);
        }
    }
    __syncthreads();
    for (int i = t; i < NCB; i += 256) {
        int c = lhist[i];
        lbase[i] = c ? atomicAdd(&cbcur[i], c) : 0;   // reserve contiguous range
        lhist[i] = 0;                                  // reuse as local offset
    }
    __syncthreads();
#pragma unroll
    for (int i = 0; i < KPT; ++i) {
        if (val[i]) {
            int cb = cbv[i];
            int p = atomicAdd(&lhist[cb], 1);
            int slot = lbase[cb] + p;
            if (slot < CAP8K) {
                part[(size_t)cb * CAP8K + slot] = pk[i];
            } else {                                   // impossible in practice; exact fallback
                int o = atomicAdd(ovf_cnt, 1);
                if (o < OVF_CAP) {
                    ovf[2 * o] = (int)(pk[i] & 0xFFFF);
                    ovf[2 * o + 1] = cb * 256 + (int)((pk[i] >> 16) & 0xFF);
                }
            }
        }
    }
}

__global__ __launch_bounds__(256) void bin_kernel(const unsigned int* __restrict__ part,
                                                  const int* __restrict__ cbcur,
                                                  const float* __restrict__ x, int N,
                                                  int* __restrict__ cursor,
                                                  unsigned short* __restrict__ bucket,
                                                  float4* __restrict__ z4,
                                                  int* __restrict__ ovf, int* __restrict__ ovf_cnt) {
    __shared__ int lcnt[256];
    __shared__ unsigned short lbuck[256 * BCAP];   // 32 KB
    int cb = blockIdx.x, t = threadIdx.x;
    lcnt[t] = 0;
    __syncthreads();
    int cnt = cbcur[cb];
    cnt = cnt < CAP8K ? cnt : CAP8K;
    size_t start = (size_t)cb * CAP8K;
    for (int i = t; i < cnt; i += 256) {
        unsigned pk = part[start + i];
        int s = pk & 0xFFFF;
        int ln = (pk >> 16) & 0xFF;
        int p = atomicAdd(&lcnt[ln], 1);
        if (p < BCAP) {
            lbuck[ln * BCAP + p] = (unsigned short)s;
        } else {
            int o = atomicAdd(ovf_cnt, 1);
            if (o < OVF_CAP) { ovf[2 * o] = s; ovf[2 * o + 1] = cb * 256 + ln; }
        }
    }
    __syncthreads();
    int d = cb * 256 + t;
    if (d < N) {
        int deg = lcnt[t];                         // exact degree (incl. >BCAP spill)
        cursor[d] = deg;
        float dd = rsqrtf((float)(deg + 1));       // +1 = self loop
        z4[d] = make_float4(dd * x[3 * d], dd * x[3 * d + 1], dd * x[3 * d + 2], dd);
    }
    const uint4* lsrc = (const uint4*)lbuck;
    uint4* gdst = (uint4*)(bucket + (size_t)cb * 256 * BCAP);
    for (int i = t; i < (256 * BCAP * 2) / 16; i += 256) gdst[i] = lsrc[i];  // dense copy
}

// ================= legacy path (N > 65535): atomic fill + z4 =================

template <typename IT>
__global__ void fill_bucket_kernel(const int* __restrict__ src, const int* __restrict__ dst, int E,
                                   int T, int* __restrict__ cursor, IT* __restrict__ bucket,
                                   int* __restrict__ ovf, int* __restrict__ ovf_cnt) {
    int tid = blockIdx.x * blockDim.x + threadIdx.x;
    int d[EPT], s[EPT], p[EPT];
    bool v[EPT];
#pragma unroll
    for (int k = 0; k < EPT; ++k) {
        int e = tid + k * T;
        v[k] = (e < E);
        d[k] = v[k] ? dst[e] : 0;
        s[k] = v[k] ? src[e] : 0;
    }
#pragma unroll
    for (int k = 0; k < EPT; ++k)
        if (v[k]) p[k] = atomicAdd(&cursor[d[k]], 1);
#pragma unroll
    for (int k = 0; k < EPT; ++k) {
        if (v[k]) {
            if (p[k] < BCAP) {
                bucket[(size_t)d[k] * BCAP + p[k]] = (IT)s[k];
            } else {
                int o = atomicAdd(ovf_cnt, 1);
                if (o < OVF_CAP) { ovf[2 * o] = s[k]; ovf[2 * o + 1] = d[k]; }
            }
        }
    }
}

__global__ void z4_kernel(const float* __restrict__ x, const int* __restrict__ cursor,
                          float4* __restrict__ z4, int N) {
    int i = blockIdx.x * blockDim.x + threadIdx.x;
    if (i < N) {
        float dd = rsqrtf((float)(cursor[i] + 1));
        z4[i] = make_float4(dd * x[3 * i], dd * x[3 * i + 1], dd * x[3 * i + 2], dd);
    }
}

// ================= layer-1 aggregation: agg4[d] = sum z4[s].xyz   [proven] ==========

template <typename IT>
__global__ void gather1_kernel(const int* __restrict__ cursor, const IT* __restrict__ bucket,
                               const float4* __restrict__ z4, float4* __restrict__ agg4, int N) {
    int wid = threadIdx.x >> 6;
    int j = threadIdx.x & 63;
    int d = blockIdx.x * 4 + wid;
    if (d >= N) return;
    int cnt = cursor[d];
    cnt = cnt < BCAP ? cnt : BCAP;
    float a0 = 0.f, a1 = 0.f, a2 = 0.f;
    if (j < cnt) {
        int s = (int)bucket[(size_t)d * BCAP + j];
        float4 zv = z4[s];
        a0 = zv.x; a1 = zv.y; a2 = zv.z;
    }
#pragma unroll
    for (int o = 32; o > 0; o >>= 1) {
        a0 += __shfl_xor(a0, o, 64);
        a1 += __shfl_xor(a1, o, 64);
        a2 += __shfl_xor(a2, o, 64);
    }
    if (j == 0) agg4[d] = make_float4(a0, a1, a2, 0.f);
}

__global__ void ovf1_kernel(const int* __restrict__ ovf, const int* __restrict__ ovf_cnt,
                            const float4* __restrict__ z4, float4* __restrict__ agg4) {
    int cnt = *ovf_cnt;
    cnt = cnt < OVF_CAP ? cnt : OVF_CAP;
    for (int t = threadIdx.x; t < cnt; t += blockDim.x) {
        int s = ovf[2 * t], d = ovf[2 * t + 1];
        float4 zv = z4[s];
        float* a = (float*)&agg4[d];
        atomicAdd(a + 0, zv.x);
        atomicAdd(a + 1, zv.y);
        atomicAdd(a + 2, zv.z);
    }
}

// ============ fused hidden GEMM: u -> relu(u@W1+b1) -> hs2 = dinv*(h@W2), bf16 out ============

__global__ __launch_bounds__(256) void hidden_kernel(const float4* __restrict__ agg4,
                                                     const float4* __restrict__ z4,
                                                     const float* __restrict__ W1,
                                                     const float* __restrict__ b1,
                                                     const float* __restrict__ W2,
                                                     unsigned short* __restrict__ hs2b, int N) {
    __shared__ float h_s[HID][NT];       // 32 KB, k-major
    __shared__ float w_s[HID * OUTC];    // 32 KB
    int t = threadIdx.x;
    int base = blockIdx.x * NT;

    for (int i = t; i < HID * OUTC; i += 256) w_s[i] = W2[i];

    {
        int n = t & 63;
        int d = base + n;
        float u0 = 0.f, u1 = 0.f, u2 = 0.f;
        if (d < N) {
            float4 zv = z4[d];
            float4 av = agg4[d];
            float dd = zv.w;
            u0 = dd * (av.x + zv.x);
            u1 = dd * (av.y + zv.y);
            u2 = dd * (av.z + zv.z);
        }
        int k0 = t >> 6;
#pragma unroll
        for (int i = 0; i < HID / 4; ++i) {
            int k = k0 + 4 * i;
            float v = u0 * W1[k] + u1 * W1[HID + k] + u2 * W1[2 * HID + k] + b1[k];
            h_s[k][n] = fmaxf(v, 0.f);
        }
    }
    __syncthreads();

    int tx = t & 15, ty = t >> 4;
    float acc[4][4] = {};
#pragma unroll 8
    for (int k = 0; k < HID; ++k) {
        float4 hv = *(const float4*)&h_s[k][ty * 4];
        float4 wv = *(const float4*)&w_s[k * OUTC + tx * 4];
        float hr[4] = {hv.x, hv.y, hv.z, hv.w};
        float wr[4] = {wv.x, wv.y, wv.z, wv.w};
#pragma unroll
        for (int r = 0; r < 4; ++r)
#pragma unroll
            for (int c = 0; c < 4; ++c) acc[r][c] = fmaf(hr[r], wr[c], acc[r][c]);
    }

#pragma unroll
    for (int r = 0; r < 4; ++r) {
        int n = ty * 4 + r;
        int d = base + n;
        if (d < N) {
            float dd = z4[d].w;
            ushort4 o;
            o.x = f2bf(dd * acc[r][0]);
            o.y = f2bf(dd * acc[r][1]);
            o.z = f2bf(dd * acc[r][2]);
            o.w = f2bf(dd * acc[r][3]);
            *(ushort4*)&hs2b[(size_t)d * OUTC + tx * 4] = o;
        }
    }
}

// ============ layer-2 gather: LDS-staged lists, 2 nodes/wave, u32 feature-pair loads ==========
// no shfl / cross-lane ops; source ids come from LDS broadcast reads (uniform per 32-lane group)

template <typename IT>
__global__ __launch_bounds__(256) void gather2_kernel(const int* __restrict__ cursor,
                                                      const IT* __restrict__ bucket,
                                                      const unsigned int* __restrict__ hs2w,
                                                      const float4* __restrict__ z4,
                                                      const float* __restrict__ b2,
                                                      float* __restrict__ out, int N) {
    __shared__ int slist[8 * BCAP];                   // 2 KB: 8 nodes' source lists
    int t = threadIdx.x;
    int base = blockIdx.x * 8;                        // 8 nodes per block
    int lim = (N - base) * BCAP;                      // entries available (legacy-path safety)
    int total = 8 * BCAP;
    if (lim > total) lim = total;
    for (int i = t; i < lim; i += 256) slist[i] = (int)bucket[(size_t)base * BCAP + i];
    __syncthreads();

    int g = t >> 5;                                   // group 0..7 -> node
    int q = t & 31;                                   // lane in group -> feature pair
    int d = base + g;
    if (d >= N) return;
    int cnt = cursor[d];
    cnt = cnt < BCAP ? cnt : BCAP;
    const int* my = &slist[g * BCAP];
    float ax = 0.f, ay = 0.f;
    int k = 0;
    for (; k + 8 <= cnt; k += 8) {                    // 8 independent row loads in flight
        unsigned u0 = hs2w[(size_t)my[k]     * 32 + q];
        unsigned u1 = hs2w[(size_t)my[k + 1] * 32 + q];
        unsigned u2 = hs2w[(size_t)my[k + 2] * 32 + q];
        unsigned u3 = hs2w[(size_t)my[k + 3] * 32 + q];
        unsigned u4 = hs2w[(size_t)my[k + 4] * 32 + q];
        unsigned u5 = hs2w[(size_t)my[k + 5] * 32 + q];
        unsigned u6 = hs2w[(size_t)my[k + 6] * 32 + q];
        unsigned u7 = hs2w[(size_t)my[k + 7] * 32 + q];
        ax += ((bf2f(u0 & 0xFFFF) + bf2f(u1 & 0xFFFF)) + (bf2f(u2 & 0xFFFF) + bf2f(u3 & 0xFFFF)))
            + ((bf2f(u4 & 0xFFFF) + bf2f(u5 & 0xFFFF)) + (bf2f(u6 & 0xFFFF) + bf2f(u7 & 0xFFFF)));
        ay += ((bf2f(u0 >> 16) + bf2f(u1 >> 16)) + (bf2f(u2 >> 16) + bf2f(u3 >> 16)))
            + ((bf2f(u4 >> 16) + bf2f(u5 >> 16)) + (bf2f(u6 >> 16) + bf2f(u7 >> 16)));
    }
    for (; k + 4 <= cnt; k += 4) {
        unsigned u0 = hs2w[(size_t)my[k]     * 32 + q];
        unsigned u1 = hs2w[(size_t)my[k + 1] * 32 + q];
        unsigned u2 = hs2w[(size_t)my[k + 2] * 32 + q];
        unsigned u3 = hs2w[(size_t)my[k + 3] * 32 + q];
        ax += (bf2f(u0 & 0xFFFF) + bf2f(u1 & 0xFFFF)) + (bf2f(u2 & 0xFFFF) + bf2f(u3 & 0xFFFF));
        ay += (bf2f(u0 >> 16) + bf2f(u1 >> 16)) + (bf2f(u2 >> 16) + bf2f(u3 >> 16));
    }
    for (; k < cnt; ++k) {
        unsigned u = hs2w[(size_t)my[k] * 32 + q];
        ax += bf2f(u & 0xFFFF);
        ay += bf2f(u >> 16);
    }
    unsigned us = hs2w[(size_t)d * 32 + q];           // self loop
    float dd = z4[d].w;
    float2 bb = *(const float2*)&b2[2 * q];
    float2 o;
    o.x = dd * (ax + bf2f(us & 0xFFFF)) + bb.x;
    o.y = dd * (ay + bf2f(us >> 16)) + bb.y;
    *(float2*)&out[(size_t)d * OUTC + 2 * q] = o;     // 256B coalesced per node
}

__global__ void ovf2_kernel(const int* __restrict__ ovf, const int* __restrict__ ovf_cnt,
                            const unsigned short* __restrict__ hs2b, const float4* __restrict__ z4,
                            float* __restrict__ out) {
    int cnt = *ovf_cnt;
    cnt = cnt < OVF_CAP ? cnt : OVF_CAP;
    for (int t = threadIdx.x; t < cnt * OUTC; t += blockDim.x) {
        int o = t >> 6, j = t & 63;
        int s = ovf[2 * o], d = ovf[2 * o + 1];
        atomicAdd(&out[(size_t)d * OUTC + j], z4[d].w * bf2f(hs2b[(size_t)s * OUTC + j]));
    }
}

static inline size_t align256(size_t v) { return (v + 255) & ~(size_t)255; }

extern "C" void kernel_launch(void* const* d_in, const int* in_sizes, int n_in,
                              void* d_out, int out_size, void* d_ws, size_t ws_size,
                              hipStream_t stream) {
    const float* x  = (const float*)d_in[0];
    const int*   ei = (const int*)d_in[1];
    const float* W1 = (const float*)d_in[2];
    const float* b1 = (const float*)d_in[3];
    const float* W2 = (const float*)d_in[4];
    const float* b2 = (const float*)d_in[5];
    float* out = (float*)d_out;

    const int N = in_sizes[0] / INC;
    const int E = in_sizes[1] / 2;
    const int* src = ei;
    const int* dst = ei + E;
    const bool u16 = (N <= 65535);
    const int NCB = (N + 255) >> 8;

    char* ws = (char*)d_ws;
    size_t off = 0;
    int*    cursor  = (int*)(ws + off);    off += align256((size_t)N * 4);
    float4* z4      = (float4*)(ws + off); off += align256((size_t)N * 16);
    float4* agg4    = (float4*)(ws + off); off += align256((size_t)N * 16);
    int*    cbcur   = (int*)(ws + off);    off += (size_t)NCBMAX * 4;      // zeroed with ovf_cnt
    int*    ovf_cnt = (int*)(ws + off);    off += 256;
    int*    ovf     = (int*)(ws + off);    off += (size_t)OVF_CAP * 8;
    unsigned int* part = (unsigned int*)(ws + off);
    off += align256(u16 ? (size_t)NCB * CAP8K * 4 : 0);
    void*   bucket  = (void*)(ws + off);
    off += align256(u16 ? (size_t)NCB * 256 * BCAP * 2 : (size_t)N * BCAP * 4);
    unsigned short* hs2b = (unsigned short*)(ws + off); off += (size_t)N * OUTC * 2;
    const unsigned int* hs2w = (const unsigned int*)hs2b;

    const int B = 256;

    if (u16) {
        hipMemsetAsync(cbcur, 0, (size_t)NCBMAX * 4 + 256, stream);        // cbcur + ovf_cnt
        int NB = (E + 256 * KPT - 1) / (256 * KPT);
        place2_kernel<<<NB, B, 0, stream>>>(src, dst, E, NCB, cbcur, part, ovf, ovf_cnt);
        bin_kernel<<<NCB, B, 0, stream>>>(part, cbcur, x, N, cursor,
                                          (unsigned short*)bucket, z4, ovf, ovf_cnt);
    } else {
        hipMemsetAsync(cursor, 0, (size_t)N * sizeof(int), stream);
        hipMemsetAsync(ovf_cnt, 0, 64, stream);
        int grid = (E + B * EPT - 1) / (B * EPT);
        int T = grid * B;
        fill_bucket_kernel<int><<<grid, B, 0, stream>>>(src, dst, E, T, cursor, (int*)bucket,
                                                        ovf, ovf_cnt);
        z4_kernel<<<(N + B - 1) / B, B, 0, stream>>>(x, cursor, z4, N);
    }

    // ---- layer 1 (3-dim gather aggregation, no atomics) ----
    if (u16)
        gather1_kernel<unsigned short><<<(N + 3) / 4, B, 0, stream>>>(
            cursor, (const unsigned short*)bucket, z4, agg4, N);
    else
        gather1_kernel<int><<<(N + 3) / 4, B, 0, stream>>>(
            cursor, (const int*)bucket, z4, agg4, N);
    ovf1_kernel<<<1, B, 0, stream>>>(ovf, ovf_cnt, z4, agg4);

    // ---- fused hidden (relu(u@W1+b1) @ W2, register-tiled GEMM, bf16 out) ----
    hidden_kernel<<<(N + NT - 1) / NT, 256, 0, stream>>>(agg4, z4, W1, b1, W2, hs2b, N);

    // ---- layer 2 gather (LDS-staged, 2 nodes/wave, u32 loads) ----
    if (u16)
        gather2_kernel<unsigned short><<<(N + 7) / 8, B, 0, stream>>>(
            cursor, (const unsigned short*)bucket, hs2w, z4, b2, out, N);
    else
        gather2_kernel<int><<<(N + 7) / 8, B, 0, stream>>>(
            cursor, (const int*)bucket, hs2w, z4, b2, out, N);
    ovf2_kernel<<<1, B, 0, stream>>>(ovf, ovf_cnt, hs2b, z4, out);
}

// Round 13
// 143.687 us; speedup vs baseline: 1.4294x; 1.0315x over previous
//
#include <hip/hip_runtime.h>
#include <hip/hip_bf16.h>

#define HID 128
#define OUTC 64
#define INC 3
#define BCAP 64        // bucket capacity per node (storage only; degree is exact)
#define OVF_CAP 8192   // overflow edge list capacity (expected usage: 0)
#define NT 64          // nodes per block in hidden GEMM
#define NCBMAX 256     // max coarse buckets (N<=65535 -> NCB<=256)
#define CAP8K 8192     // slots per coarse bucket in part[] (mean 4082, 64 sigma headroom)
#define KPT 8          // edges per thread in place2
#define EPT 4          // legacy path

static __device__ __forceinline__ unsigned short f2bf(float f) {
    __hip_bfloat16 b = __float2bfloat16(f);
    return *reinterpret_cast<unsigned short*>(&b);
}
static __device__ __forceinline__ float bf2f(unsigned short u) {
    __hip_bfloat16 b = *reinterpret_cast<__hip_bfloat16*>(&u);
    return __bfloat162float(b);
}

// ================= capacity-based counting-sort bucket build (N <= 65535 path) =================
// [proven round 11/12]

__global__ __launch_bounds__(256) void place2_kernel(const int* __restrict__ src,
                                                     const int* __restrict__ dst, int E, int NCB,
                                                     int* __restrict__ cbcur,
                                                     unsigned int* __restrict__ part,
                                                     int* __restrict__ ovf, int* __restrict__ ovf_cnt) {
    __shared__ int lhist[NCBMAX];
    __shared__ int lbase[NCBMAX];
    int t = threadIdx.x;
    int s0 = blockIdx.x * (256 * KPT);
    for (int i = t; i < NCBMAX; i += 256) lhist[i] = 0;
    __syncthreads();

    unsigned pk[KPT];
    int cbv[KPT];
    bool val[KPT];
#pragma unroll
    for (int i = 0; i < KPT; ++i) {
        int e = s0 + t + i * 256;                 // coalesced
        val[i] = (e < E);
        if (val[i]) {
            int d = dst[e], s = src[e];
            cbv[i] = d >> 8;
            pk[i] = (unsigned)s | ((unsigned)(d & 255) << 16);
            atomicAdd(&lhist[cbv[i]], 1);
        }
    }
    __syncthreads();
    for (int i = t; i < NCB; i += 256) {
        int c = lhist[i];
        lbase[i] = c ? atomicAdd(&cbcur[i], c) : 0;   // reserve contiguous range
        lhist[i] = 0;                                  // reuse as local offset
    }
    __syncthreads();
#pragma unroll
    for (int i = 0; i < KPT; ++i) {
        if (val[i]) {
            int cb = cbv[i];
            int p = atomicAdd(&lhist[cb], 1);
            int slot = lbase[cb] + p;
            if (slot < CAP8K) {
                part[(size_t)cb * CAP8K + slot] = pk[i];
            } else {                                   // impossible in practice; exact fallback
                int o = atomicAdd(ovf_cnt, 1);
                if (o < OVF_CAP) {
                    ovf[2 * o] = (int)(pk[i] & 0xFFFF);
                    ovf[2 * o + 1] = cb * 256 + (int)((pk[i] >> 16) & 0xFF);
                }
            }
        }
    }
}

__global__ __launch_bounds__(256) void bin_kernel(const unsigned int* __restrict__ part,
                                                  const int* __restrict__ cbcur,
                                                  const float* __restrict__ x, int N,
                                                  int* __restrict__ cursor,
                                                  unsigned short* __restrict__ bucket,
                                                  float4* __restrict__ z4,
                                                  int* __restrict__ ovf, int* __restrict__ ovf_cnt) {
    __shared__ int lcnt[256];
    __shared__ unsigned short lbuck[256 * BCAP];   // 32 KB
    int cb = blockIdx.x, t = threadIdx.x;
    lcnt[t] = 0;
    __syncthreads();
    int cnt = cbcur[cb];
    cnt = cnt < CAP8K ? cnt : CAP8K;
    size_t start = (size_t)cb * CAP8K;
    for (int i = t; i < cnt; i += 256) {
        unsigned pk = part[start + i];
        int s = pk & 0xFFFF;
        int ln = (pk >> 16) & 0xFF;
        int p = atomicAdd(&lcnt[ln], 1);
        if (p < BCAP) {
            lbuck[ln * BCAP + p] = (unsigned short)s;
        } else {
            int o = atomicAdd(ovf_cnt, 1);
            if (o < OVF_CAP) { ovf[2 * o] = s; ovf[2 * o + 1] = cb * 256 + ln; }
        }
    }
    __syncthreads();
    int d = cb * 256 + t;
    if (d < N) {
        int deg = lcnt[t];                         // exact degree (incl. >BCAP spill)
        cursor[d] = deg;
        float dd = rsqrtf((float)(deg + 1));       // +1 = self loop
        z4[d] = make_float4(dd * x[3 * d], dd * x[3 * d + 1], dd * x[3 * d + 2], dd);
    }
    const uint4* lsrc = (const uint4*)lbuck;
    uint4* gdst = (uint4*)(bucket + (size_t)cb * 256 * BCAP);
    for (int i = t; i < (256 * BCAP * 2) / 16; i += 256) gdst[i] = lsrc[i];  // dense copy
}

// ================= legacy path (N > 65535): atomic fill + z4 =================

template <typename IT>
__global__ void fill_bucket_kernel(const int* __restrict__ src, const int* __restrict__ dst, int E,
                                   int T, int* __restrict__ cursor, IT* __restrict__ bucket,
                                   int* __restrict__ ovf, int* __restrict__ ovf_cnt) {
    int tid = blockIdx.x * blockDim.x + threadIdx.x;
    int d[EPT], s[EPT], p[EPT];
    bool v[EPT];
#pragma unroll
    for (int k = 0; k < EPT; ++k) {
        int e = tid + k * T;
        v[k] = (e < E);
        d[k] = v[k] ? dst[e] : 0;
        s[k] = v[k] ? src[e] : 0;
    }
#pragma unroll
    for (int k = 0; k < EPT; ++k)
        if (v[k]) p[k] = atomicAdd(&cursor[d[k]], 1);
#pragma unroll
    for (int k = 0; k < EPT; ++k) {
        if (v[k]) {
            if (p[k] < BCAP) {
                bucket[(size_t)d[k] * BCAP + p[k]] = (IT)s[k];
            } else {
                int o = atomicAdd(ovf_cnt, 1);
                if (o < OVF_CAP) { ovf[2 * o] = s[k]; ovf[2 * o + 1] = d[k]; }
            }
        }
    }
}

__global__ void z4_kernel(const float* __restrict__ x, const int* __restrict__ cursor,
                          float4* __restrict__ z4, int N) {
    int i = blockIdx.x * blockDim.x + threadIdx.x;
    if (i < N) {
        float dd = rsqrtf((float)(cursor[i] + 1));
        z4[i] = make_float4(dd * x[3 * i], dd * x[3 * i + 1], dd * x[3 * i + 2], dd);
    }
}

// ================= layer-1 aggregation: agg4[d] = sum z4[s].xyz   [proven] ==========

template <typename IT>
__global__ void gather1_kernel(const int* __restrict__ cursor, const IT* __restrict__ bucket,
                               const float4* __restrict__ z4, float4* __restrict__ agg4, int N) {
    int wid = threadIdx.x >> 6;
    int j = threadIdx.x & 63;
    int d = blockIdx.x * 4 + wid;
    if (d >= N) return;
    int cnt = cursor[d];
    cnt = cnt < BCAP ? cnt : BCAP;
    float a0 = 0.f, a1 = 0.f, a2 = 0.f;
    if (j < cnt) {
        int s = (int)bucket[(size_t)d * BCAP + j];
        float4 zv = z4[s];
        a0 = zv.x; a1 = zv.y; a2 = zv.z;
    }
#pragma unroll
    for (int o = 32; o > 0; o >>= 1) {
        a0 += __shfl_xor(a0, o, 64);
        a1 += __shfl_xor(a1, o, 64);
        a2 += __shfl_xor(a2, o, 64);
    }
    if (j == 0) agg4[d] = make_float4(a0, a1, a2, 0.f);
}

// ============ fused hidden GEMM: u -> relu(u@W1+b1) -> hs2 = dinv*(h@W2), bf16 out ============
// layer-1 overflow contributions inlined (oc==0 in practice -> one broadcast load)

__global__ __launch_bounds__(256) void hidden_kernel(const float4* __restrict__ agg4,
                                                     const float4* __restrict__ z4,
                                                     const float* __restrict__ W1,
                                                     const float* __restrict__ b1,
                                                     const float* __restrict__ W2,
                                                     unsigned short* __restrict__ hs2b, int N,
                                                     const int* __restrict__ ovf,
                                                     const int* __restrict__ ovf_cnt) {
    __shared__ float h_s[HID][NT];       // 32 KB, k-major
    __shared__ float w_s[HID * OUTC];    // 32 KB
    int t = threadIdx.x;
    int base = blockIdx.x * NT;

    for (int i = t; i < HID * OUTC; i += 256) w_s[i] = W2[i];

    {
        int n = t & 63;
        int d = base + n;
        float u0 = 0.f, u1 = 0.f, u2 = 0.f;
        if (d < N) {
            float4 zv = z4[d];
            float4 av = agg4[d];
            float dd = zv.w;
            u0 = dd * (av.x + zv.x);
            u1 = dd * (av.y + zv.y);
            u2 = dd * (av.z + zv.z);
            int oc = *ovf_cnt;                        // broadcast load; 0 in practice
            if (oc > 0) {
                oc = oc < OVF_CAP ? oc : OVF_CAP;
                for (int i = 0; i < oc; ++i) {
                    if (ovf[2 * i + 1] == d) {
                        float4 zs = z4[ovf[2 * i]];
                        u0 += dd * zs.x; u1 += dd * zs.y; u2 += dd * zs.z;
                    }
                }
            }
        }
        int k0 = t >> 6;
#pragma unroll
        for (int i = 0; i < HID / 4; ++i) {
            int k = k0 + 4 * i;
            float v = u0 * W1[k] + u1 * W1[HID + k] + u2 * W1[2 * HID + k] + b1[k];
            h_s[k][n] = fmaxf(v, 0.f);
        }
    }
    __syncthreads();

    int tx = t & 15, ty = t >> 4;
    float acc[4][4] = {};
#pragma unroll 8
    for (int k = 0; k < HID; ++k) {
        float4 hv = *(const float4*)&h_s[k][ty * 4];
        float4 wv = *(const float4*)&w_s[k * OUTC + tx * 4];
        float hr[4] = {hv.x, hv.y, hv.z, hv.w};
        float wr[4] = {wv.x, wv.y, wv.z, wv.w};
#pragma unroll
        for (int r = 0; r < 4; ++r)
#pragma unroll
            for (int c = 0; c < 4; ++c) acc[r][c] = fmaf(hr[r], wr[c], acc[r][c]);
    }

#pragma unroll
    for (int r = 0; r < 4; ++r) {
        int n = ty * 4 + r;
        int d = base + n;
        if (d < N) {
            float dd = z4[d].w;
            ushort4 o;
            o.x = f2bf(dd * acc[r][0]);
            o.y = f2bf(dd * acc[r][1]);
            o.z = f2bf(dd * acc[r][2]);
            o.w = f2bf(dd * acc[r][3]);
            *(ushort4*)&hs2b[(size_t)d * OUTC + tx * 4] = o;
        }
    }
}

// ============ layer-2 gather: LDS-staged lists, 4 nodes/wave, uint2 feature-quad loads ==========
// no cross-lane ops; source ids from LDS broadcast (uniform per 16-lane group);
// layer-2 overflow inlined (oc==0 in practice)

template <typename IT>
__global__ __launch_bounds__(256) void gather2_kernel(const int* __restrict__ cursor,
                                                      const IT* __restrict__ bucket,
                                                      const uint2* __restrict__ hs2v,
                                                      const float4* __restrict__ z4,
                                                      const float* __restrict__ b2,
                                                      float* __restrict__ out, int N,
                                                      const int* __restrict__ ovf,
                                                      const int* __restrict__ ovf_cnt) {
    __shared__ int slist[16 * BCAP];                  // 4 KB: 16 nodes' source lists
    int t = threadIdx.x;
    int base = blockIdx.x * 16;                       // 16 nodes per block
    int lim = (N - base) * BCAP;                      // entries available
    int total = 16 * BCAP;
    if (lim > total) lim = total;
    for (int i = t; i < lim; i += 256) slist[i] = (int)bucket[(size_t)base * BCAP + i];
    __syncthreads();

    int g = t >> 4;                                   // group 0..15 -> node
    int q = t & 15;                                   // lane -> feature quad (4q..4q+3)
    int d = base + g;
    if (d >= N) return;
    int cnt = cursor[d];
    cnt = cnt < BCAP ? cnt : BCAP;
    const int* my = &slist[g * BCAP];
    float a0 = 0.f, a1 = 0.f, a2 = 0.f, a3 = 0.f;
    int k = 0;
    for (; k + 8 <= cnt; k += 8) {                    // 8 independent row loads in flight
        uint2 u0 = hs2v[(size_t)my[k]     * 16 + q];
        uint2 u1 = hs2v[(size_t)my[k + 1] * 16 + q];
        uint2 u2 = hs2v[(size_t)my[k + 2] * 16 + q];
        uint2 u3 = hs2v[(size_t)my[k + 3] * 16 + q];
        uint2 u4 = hs2v[(size_t)my[k + 4] * 16 + q];
        uint2 u5 = hs2v[(size_t)my[k + 5] * 16 + q];
        uint2 u6 = hs2v[(size_t)my[k + 6] * 16 + q];
        uint2 u7 = hs2v[(size_t)my[k + 7] * 16 + q];
        a0 += ((bf2f(u0.x & 0xFFFF) + bf2f(u1.x & 0xFFFF)) + (bf2f(u2.x & 0xFFFF) + bf2f(u3.x & 0xFFFF)))
            + ((bf2f(u4.x & 0xFFFF) + bf2f(u5.x & 0xFFFF)) + (bf2f(u6.x & 0xFFFF) + bf2f(u7.x & 0xFFFF)));
        a1 += ((bf2f(u0.x >> 16) + bf2f(u1.x >> 16)) + (bf2f(u2.x >> 16) + bf2f(u3.x >> 16)))
            + ((bf2f(u4.x >> 16) + bf2f(u5.x >> 16)) + (bf2f(u6.x >> 16) + bf2f(u7.x >> 16)));
        a2 += ((bf2f(u0.y & 0xFFFF) + bf2f(u1.y & 0xFFFF)) + (bf2f(u2.y & 0xFFFF) + bf2f(u3.y & 0xFFFF)))
            + ((bf2f(u4.y & 0xFFFF) + bf2f(u5.y & 0xFFFF)) + (bf2f(u6.y & 0xFFFF) + bf2f(u7.y & 0xFFFF)));
        a3 += ((bf2f(u0.y >> 16) + bf2f(u1.y >> 16)) + (bf2f(u2.y >> 16) + bf2f(u3.y >> 16)))
            + ((bf2f(u4.y >> 16) + bf2f(u5.y >> 16)) + (bf2f(u6.y >> 16) + bf2f(u7.y >> 16)));
    }
    for (; k + 4 <= cnt; k += 4) {
        uint2 u0 = hs2v[(size_t)my[k]     * 16 + q];
        uint2 u1 = hs2v[(size_t)my[k + 1] * 16 + q];
        uint2 u2 = hs2v[(size_t)my[k + 2] * 16 + q];
        uint2 u3 = hs2v[(size_t)my[k + 3] * 16 + q];
        a0 += (bf2f(u0.x & 0xFFFF) + bf2f(u1.x & 0xFFFF)) + (bf2f(u2.x & 0xFFFF) + bf2f(u3.x & 0xFFFF));
        a1 += (bf2f(u0.x >> 16) + bf2f(u1.x >> 16)) + (bf2f(u2.x >> 16) + bf2f(u3.x >> 16));
        a2 += (bf2f(u0.y & 0xFFFF) + bf2f(u1.y & 0xFFFF)) + (bf2f(u2.y & 0xFFFF) + bf2f(u3.y & 0xFFFF));
        a3 += (bf2f(u0.y >> 16) + bf2f(u1.y >> 16)) + (bf2f(u2.y >> 16) + bf2f(u3.y >> 16));
    }
    for (; k < cnt; ++k) {
        uint2 u = hs2v[(size_t)my[k] * 16 + q];
        a0 += bf2f(u.x & 0xFFFF);
        a1 += bf2f(u.x >> 16);
        a2 += bf2f(u.y & 0xFFFF);
        a3 += bf2f(u.y >> 16);
    }
    int oc = *ovf_cnt;                                // broadcast load; 0 in practice
    if (oc > 0) {
        oc = oc < OVF_CAP ? oc : OVF_CAP;
        for (int i = 0; i < oc; ++i) {
            if (ovf[2 * i + 1] == d) {
                uint2 u = hs2v[(size_t)ovf[2 * i] * 16 + q];
                a0 += bf2f(u.x & 0xFFFF);
                a1 += bf2f(u.x >> 16);
                a2 += bf2f(u.y & 0xFFFF);
                a3 += bf2f(u.y >> 16);
            }
        }
    }
    uint2 us = hs2v[(size_t)d * 16 + q];              // self loop
    float dd = z4[d].w;
    float4 bb = *(const float4*)&b2[4 * q];
    float4 o;
    o.x = dd * (a0 + bf2f(us.x & 0xFFFF)) + bb.x;
    o.y = dd * (a1 + bf2f(us.x >> 16)) + bb.y;
    o.z = dd * (a2 + bf2f(us.y & 0xFFFF)) + bb.z;
    o.w = dd * (a3 + bf2f(us.y >> 16)) + bb.w;
    *(float4*)&out[(size_t)d * OUTC + 4 * q] = o;     // 256B coalesced per node
}

static inline size_t align256(size_t v) { return (v + 255) & ~(size_t)255; }

extern "C" void kernel_launch(void* const* d_in, const int* in_sizes, int n_in,
                              void* d_out, int out_size, void* d_ws, size_t ws_size,
                              hipStream_t stream) {
    const float* x  = (const float*)d_in[0];
    const int*   ei = (const int*)d_in[1];
    const float* W1 = (const float*)d_in[2];
    const float* b1 = (const float*)d_in[3];
    const float* W2 = (const float*)d_in[4];
    const float* b2 = (const float*)d_in[5];
    float* out = (float*)d_out;

    const int N = in_sizes[0] / INC;
    const int E = in_sizes[1] / 2;
    const int* src = ei;
    const int* dst = ei + E;
    const bool u16 = (N <= 65535);
    const int NCB = (N + 255) >> 8;

    char* ws = (char*)d_ws;
    size_t off = 0;
    int*    cursor  = (int*)(ws + off);    off += align256((size_t)N * 4);
    float4* z4      = (float4*)(ws + off); off += align256((size_t)N * 16);
    float4* agg4    = (float4*)(ws + off); off += align256((size_t)N * 16);
    int*    cbcur   = (int*)(ws + off);    off += (size_t)NCBMAX * 4;      // zeroed with ovf_cnt
    int*    ovf_cnt = (int*)(ws + off);    off += 256;
    int*    ovf     = (int*)(ws + off);    off += (size_t)OVF_CAP * 8;
    unsigned int* part = (unsigned int*)(ws + off);
    off += align256(u16 ? (size_t)NCB * CAP8K * 4 : 0);
    void*   bucket  = (void*)(ws + off);
    off += align256(u16 ? (size_t)NCB * 256 * BCAP * 2 : (size_t)N * BCAP * 4);
    unsigned short* hs2b = (unsigned short*)(ws + off); off += (size_t)N * OUTC * 2;
    const uint2* hs2v = (const uint2*)hs2b;

    const int B = 256;

    if (u16) {
        hipMemsetAsync(cbcur, 0, (size_t)NCBMAX * 4 + 256, stream);        // cbcur + ovf_cnt
        int NB = (E + 256 * KPT - 1) / (256 * KPT);
        place2_kernel<<<NB, B, 0, stream>>>(src, dst, E, NCB, cbcur, part, ovf, ovf_cnt);
        bin_kernel<<<NCB, B, 0, stream>>>(part, cbcur, x, N, cursor,
                                          (unsigned short*)bucket, z4, ovf, ovf_cnt);
    } else {
        hipMemsetAsync(cursor, 0, (size_t)N * sizeof(int), stream);
        hipMemsetAsync(ovf_cnt, 0, 64, stream);
        int grid = (E + B * EPT - 1) / (B * EPT);
        int T = grid * B;
        fill_bucket_kernel<int><<<grid, B, 0, stream>>>(src, dst, E, T, cursor, (int*)bucket,
                                                        ovf, ovf_cnt);
        z4_kernel<<<(N + B - 1) / B, B, 0, stream>>>(x, cursor, z4, N);
    }

    // ---- layer 1 (3-dim gather aggregation, no atomics) ----
    if (u16)
        gather1_kernel<unsigned short><<<(N + 3) / 4, B, 0, stream>>>(
            cursor, (const unsigned short*)bucket, z4, agg4, N);
    else
        gather1_kernel<int><<<(N + 3) / 4, B, 0, stream>>>(
            cursor, (const int*)bucket, z4, agg4, N);

    // ---- fused hidden (relu(u@W1+b1) @ W2, register-tiled GEMM, bf16 out; l1-ovf inlined) ----
    hidden_kernel<<<(N + NT - 1) / NT, 256, 0, stream>>>(agg4, z4, W1, b1, W2, hs2b, N,
                                                         ovf, ovf_cnt);

    // ---- layer 2 gather (LDS-staged, 4 nodes/wave, uint2 loads; l2-ovf inlined) ----
    if (u16)
        gather2_kernel<unsigned short><<<(N + 15) / 16, B, 0, stream>>>(
            cursor, (const unsigned short*)bucket, hs2v, z4, b2, out, N, ovf, ovf_cnt);
    else
        gather2_kernel<int><<<(N + 15) / 16, B, 0, stream>>>(
            cursor, (const int*)bucket, hs2v, z4, b2, out, N, ovf, ovf_cnt);
}

// Round 14
// 137.908 us; speedup vs baseline: 1.4893x; 1.0419x over previous
//
#include <hip/hip_runtime.h>
#include <hip/hip_bf16.h>

#define HID 128
#define OUTC 64
#define INC 3
#define BCAP 64        // bucket capacity per node (storage only; degree is exact)
#define OVF_CAP 8192   // overflow edge list capacity (expected usage: 0)
#define NT 64          // nodes per block in hidden GEMM
#define NCBMAX 256     // max coarse buckets (N<=65535 -> NCB<=256)
#define CAP8K 8192     // slots per coarse bucket in part[] (mean 4082, 64 sigma headroom)
#define KPT 8          // edges per thread in place2
#define EPT 4          // legacy path

static __device__ __forceinline__ unsigned short f2bf(float f) {
    __hip_bfloat16 b = __float2bfloat16(f);
    return *reinterpret_cast<unsigned short*>(&b);
}
static __device__ __forceinline__ float bf2f(unsigned short u) {
    __hip_bfloat16 b = *reinterpret_cast<__hip_bfloat16*>(&u);
    return __bfloat162float(b);
}

// ================= capacity-based counting-sort bucket build (N <= 65535 path) =================
// [proven rounds 11-13]

__global__ __launch_bounds__(256) void place2_kernel(const int* __restrict__ src,
                                                     const int* __restrict__ dst, int E, int NCB,
                                                     int* __restrict__ cbcur,
                                                     unsigned int* __restrict__ part,
                                                     int* __restrict__ ovf, int* __restrict__ ovf_cnt) {
    __shared__ int lhist[NCBMAX];
    __shared__ int lbase[NCBMAX];
    int t = threadIdx.x;
    int s0 = blockIdx.x * (256 * KPT);
    for (int i = t; i < NCBMAX; i += 256) lhist[i] = 0;
    __syncthreads();

    unsigned pk[KPT];
    int cbv[KPT];
    bool val[KPT];
#pragma unroll
    for (int i = 0; i < KPT; ++i) {
        int e = s0 + t + i * 256;                 // coalesced
        val[i] = (e < E);
        if (val[i]) {
            int d = dst[e], s = src[e];
            cbv[i] = d >> 8;
            pk[i] = (unsigned)s | ((unsigned)(d & 255) << 16);
            atomicAdd(&lhist[cbv[i]], 1);
        }
    }
    __syncthreads();
    for (int i = t; i < NCB; i += 256) {
        int c = lhist[i];
        lbase[i] = c ? atomicAdd(&cbcur[i], c) : 0;   // reserve contiguous range
        lhist[i] = 0;                                  // reuse as local offset
    }
    __syncthreads();
#pragma unroll
    for (int i = 0; i < KPT; ++i) {
        if (val[i]) {
            int cb = cbv[i];
            int p = atomicAdd(&lhist[cb], 1);
            int slot = lbase[cb] + p;
            if (slot < CAP8K) {
                part[(size_t)cb * CAP8K + slot] = pk[i];
            } else {                                   // impossible in practice; exact fallback
                int o = atomicAdd(ovf_cnt, 1);
                if (o < OVF_CAP) {
                    ovf[2 * o] = (int)(pk[i] & 0xFFFF);
                    ovf[2 * o + 1] = cb * 256 + (int)((pk[i] >> 16) & 0xFF);
                }
            }
        }
    }
}

__global__ __launch_bounds__(256) void bin_kernel(const unsigned int* __restrict__ part,
                                                  const int* __restrict__ cbcur,
                                                  const float* __restrict__ x, int N,
                                                  int* __restrict__ cursor,
                                                  unsigned short* __restrict__ bucket,
                                                  float4* __restrict__ z4,
                                                  int* __restrict__ ovf, int* __restrict__ ovf_cnt) {
    __shared__ int lcnt[256];
    __shared__ unsigned short lbuck[256 * BCAP];   // 32 KB
    int cb = blockIdx.x, t = threadIdx.x;
    lcnt[t] = 0;
    __syncthreads();
    int cnt = cbcur[cb];
    cnt = cnt < CAP8K ? cnt : CAP8K;
    size_t start = (size_t)cb * CAP8K;
    for (int i = t; i < cnt; i += 256) {
        unsigned pk = part[start + i];
        int s = pk & 0xFFFF;
        int ln = (pk >> 16) & 0xFF;
        int p = atomicAdd(&lcnt[ln], 1);
        if (p < BCAP) {
            lbuck[ln * BCAP + p] = (unsigned short)s;
        } else {
            int o = atomicAdd(ovf_cnt, 1);
            if (o < OVF_CAP) { ovf[2 * o] = s; ovf[2 * o + 1] = cb * 256 + ln; }
        }
    }
    __syncthreads();
    int d = cb * 256 + t;
    if (d < N) {
        int deg = lcnt[t];                         // exact degree (incl. >BCAP spill)
        cursor[d] = deg;
        float dd = rsqrtf((float)(deg + 1));       // +1 = self loop
        z4[d] = make_float4(dd * x[3 * d], dd * x[3 * d + 1], dd * x[3 * d + 2], dd);
    }
    const uint4* lsrc = (const uint4*)lbuck;
    uint4* gdst = (uint4*)(bucket + (size_t)cb * 256 * BCAP);
    for (int i = t; i < (256 * BCAP * 2) / 16; i += 256) gdst[i] = lsrc[i];  // dense copy
}

// ================= legacy path (N > 65535): atomic fill + z4 =================

template <typename IT>
__global__ void fill_bucket_kernel(const int* __restrict__ src, const int* __restrict__ dst, int E,
                                   int T, int* __restrict__ cursor, IT* __restrict__ bucket,
                                   int* __restrict__ ovf, int* __restrict__ ovf_cnt) {
    int tid = blockIdx.x * blockDim.x + threadIdx.x;
    int d[EPT], s[EPT], p[EPT];
    bool v[EPT];
#pragma unroll
    for (int k = 0; k < EPT; ++k) {
        int e = tid + k * T;
        v[k] = (e < E);
        d[k] = v[k] ? dst[e] : 0;
        s[k] = v[k] ? src[e] : 0;
    }
#pragma unroll
    for (int k = 0; k < EPT; ++k)
        if (v[k]) p[k] = atomicAdd(&cursor[d[k]], 1);
#pragma unroll
    for (int k = 0; k < EPT; ++k) {
        if (v[k]) {
            if (p[k] < BCAP) {
                bucket[(size_t)d[k] * BCAP + p[k]] = (IT)s[k];
            } else {
                int o = atomicAdd(ovf_cnt, 1);
                if (o < OVF_CAP) { ovf[2 * o] = s[k]; ovf[2 * o + 1] = d[k]; }
            }
        }
    }
}

__global__ void z4_kernel(const float* __restrict__ x, const int* __restrict__ cursor,
                          float4* __restrict__ z4, int N) {
    int i = blockIdx.x * blockDim.x + threadIdx.x;
    if (i < N) {
        float dd = rsqrtf((float)(cursor[i] + 1));
        z4[i] = make_float4(dd * x[3 * i], dd * x[3 * i + 1], dd * x[3 * i + 2], dd);
    }
}

// ==== fused hidden: layer-1 gather + relu(u@W1+b1) @ W2 GEMM, bf16 out ====
// stage 1a: 4 lanes/node partial-sum z4[s], combine via shfl_xor(16/32) at wave-uniform
// point (proven gather1 butterfly idiom); partials parked in u_s (aliases h_s, LDS = 64 KB)

template <typename IT>
__global__ __launch_bounds__(256) void hidden_kernel(const IT* __restrict__ bucket,
                                                     const int* __restrict__ cursor,
                                                     const float4* __restrict__ z4,
                                                     const float* __restrict__ W1,
                                                     const float* __restrict__ b1,
                                                     const float* __restrict__ W2,
                                                     unsigned short* __restrict__ hs2b, int N,
                                                     const int* __restrict__ ovf,
                                                     const int* __restrict__ ovf_cnt) {
    __shared__ float h_s[HID][NT];       // 32 KB, k-major; first 192 floats alias u_s in stage 1
    __shared__ float w_s[HID * OUTC];    // 32 KB
    float* u_s = &h_s[0][0];             // [64][3] agg parking, 768 B
    int t = threadIdx.x;
    int base = blockIdx.x * NT;

    for (int i = t; i < HID * OUTC; i += 256) w_s[i] = W2[i];

    // stage 1a: gather agg for the block's 64 nodes
    {
        int g = (t & 63) & 15;           // node group within wave
        int r = (t & 63) >> 4;           // 0..3 split of the bucket list
        int n = (t >> 6) * 16 + g;       // wave w owns nodes w*16..w*16+15
        int d = base + n;
        float p0 = 0.f, p1 = 0.f, p2 = 0.f;
        if (d < N) {
            int cnt = cursor[d];
            cnt = cnt < BCAP ? cnt : BCAP;
            for (int k = r; k < cnt; k += 4) {
                int s = (int)bucket[(size_t)d * BCAP + k];
                float4 zv = z4[s];
                p0 += zv.x; p1 += zv.y; p2 += zv.z;
            }
        }
        // combine the 4 per-node partials (lanes l, l^16, l^32, l^48)
        p0 += __shfl_xor(p0, 16, 64); p0 += __shfl_xor(p0, 32, 64);
        p1 += __shfl_xor(p1, 16, 64); p1 += __shfl_xor(p1, 32, 64);
        p2 += __shfl_xor(p2, 16, 64); p2 += __shfl_xor(p2, 32, 64);
        if (r == 0 && d < N) {
            int oc = *ovf_cnt;                        // broadcast load; 0 in practice
            if (oc > 0) {
                oc = oc < OVF_CAP ? oc : OVF_CAP;
                for (int i = 0; i < oc; ++i) {
                    if (ovf[2 * i + 1] == d) {
                        float4 zs = z4[ovf[2 * i]];
                        p0 += zs.x; p1 += zs.y; p2 += zs.z;
                    }
                }
            }
            u_s[n * 3 + 0] = p0;
            u_s[n * 3 + 1] = p1;
            u_s[n * 3 + 2] = p2;
        }
    }
    __syncthreads();

    // stage 1b: u into registers (4 threads per node read the same agg)
    int n = t & 63;
    int d = base + n;
    float u0 = 0.f, u1 = 0.f, u2 = 0.f;
    if (d < N) {
        float a0 = u_s[n * 3], a1 = u_s[n * 3 + 1], a2 = u_s[n * 3 + 2];
        float4 zv = z4[d];
        float dd = zv.w;
        u0 = dd * (a0 + zv.x);
        u1 = dd * (a1 + zv.y);
        u2 = dd * (a2 + zv.z);
    }
    __syncthreads();                     // all u_s reads done before h_s writes

    // stage 1c: h = relu(u @ W1 + b1)
    {
        int k0 = t >> 6;
#pragma unroll
        for (int i = 0; i < HID / 4; ++i) {
            int k = k0 + 4 * i;
            float v = u0 * W1[k] + u1 * W1[HID + k] + u2 * W1[2 * HID + k] + b1[k];
            h_s[k][n] = fmaxf(v, 0.f);
        }
    }
    __syncthreads();

    // stage 2: 16x16 thread grid, 4x4 register tile
    int tx = t & 15, ty = t >> 4;
    float acc[4][4] = {};
#pragma unroll 8
    for (int k = 0; k < HID; ++k) {
        float4 hv = *(const float4*)&h_s[k][ty * 4];
        float4 wv = *(const float4*)&w_s[k * OUTC + tx * 4];
        float hr[4] = {hv.x, hv.y, hv.z, hv.w};
        float wr[4] = {wv.x, wv.y, wv.z, wv.w};
#pragma unroll
        for (int r = 0; r < 4; ++r)
#pragma unroll
            for (int c = 0; c < 4; ++c) acc[r][c] = fmaf(hr[r], wr[c], acc[r][c]);
    }

#pragma unroll
    for (int r = 0; r < 4; ++r) {
        int nn = ty * 4 + r;
        int dd_i = base + nn;
        if (dd_i < N) {
            float dd = z4[dd_i].w;
            ushort4 o;
            o.x = f2bf(dd * acc[r][0]);
            o.y = f2bf(dd * acc[r][1]);
            o.z = f2bf(dd * acc[r][2]);
            o.w = f2bf(dd * acc[r][3]);
            *(ushort4*)&hs2b[(size_t)dd_i * OUTC + tx * 4] = o;
        }
    }
}

// ============ layer-2 gather: LDS-staged lists, 4 nodes/wave, uint2 feature-quad loads ==========
// [proven round 13]

template <typename IT>
__global__ __launch_bounds__(256) void gather2_kernel(const int* __restrict__ cursor,
                                                      const IT* __restrict__ bucket,
                                                      const uint2* __restrict__ hs2v,
                                                      const float4* __restrict__ z4,
                                                      const float* __restrict__ b2,
                                                      float* __restrict__ out, int N,
                                                      const int* __restrict__ ovf,
                                                      const int* __restrict__ ovf_cnt) {
    __shared__ int slist[16 * BCAP];                  // 4 KB: 16 nodes' source lists
    int t = threadIdx.x;
    int base = blockIdx.x * 16;                       // 16 nodes per block
    int lim = (N - base) * BCAP;                      // entries available
    int total = 16 * BCAP;
    if (lim > total) lim = total;
    for (int i = t; i < lim; i += 256) slist[i] = (int)bucket[(size_t)base * BCAP + i];
    __syncthreads();

    int g = t >> 4;                                   // group 0..15 -> node
    int q = t & 15;                                   // lane -> feature quad (4q..4q+3)
    int d = base + g;
    if (d >= N) return;
    int cnt = cursor[d];
    cnt = cnt < BCAP ? cnt : BCAP;
    const int* my = &slist[g * BCAP];
    float a0 = 0.f, a1 = 0.f, a2 = 0.f, a3 = 0.f;
    int k = 0;
    for (; k + 8 <= cnt; k += 8) {                    // 8 independent row loads in flight
        uint2 u0 = hs2v[(size_t)my[k]     * 16 + q];
        uint2 u1 = hs2v[(size_t)my[k + 1] * 16 + q];
        uint2 u2 = hs2v[(size_t)my[k + 2] * 16 + q];
        uint2 u3 = hs2v[(size_t)my[k + 3] * 16 + q];
        uint2 u4 = hs2v[(size_t)my[k + 4] * 16 + q];
        uint2 u5 = hs2v[(size_t)my[k + 5] * 16 + q];
        uint2 u6 = hs2v[(size_t)my[k + 6] * 16 + q];
        uint2 u7 = hs2v[(size_t)my[k + 7] * 16 + q];
        a0 += ((bf2f(u0.x & 0xFFFF) + bf2f(u1.x & 0xFFFF)) + (bf2f(u2.x & 0xFFFF) + bf2f(u3.x & 0xFFFF)))
            + ((bf2f(u4.x & 0xFFFF) + bf2f(u5.x & 0xFFFF)) + (bf2f(u6.x & 0xFFFF) + bf2f(u7.x & 0xFFFF)));
        a1 += ((bf2f(u0.x >> 16) + bf2f(u1.x >> 16)) + (bf2f(u2.x >> 16) + bf2f(u3.x >> 16)))
            + ((bf2f(u4.x >> 16) + bf2f(u5.x >> 16)) + (bf2f(u6.x >> 16) + bf2f(u7.x >> 16)));
        a2 += ((bf2f(u0.y & 0xFFFF) + bf2f(u1.y & 0xFFFF)) + (bf2f(u2.y & 0xFFFF) + bf2f(u3.y & 0xFFFF)))
            + ((bf2f(u4.y & 0xFFFF) + bf2f(u5.y & 0xFFFF)) + (bf2f(u6.y & 0xFFFF) + bf2f(u7.y & 0xFFFF)));
        a3 += ((bf2f(u0.y >> 16) + bf2f(u1.y >> 16)) + (bf2f(u2.y >> 16) + bf2f(u3.y >> 16)))
            + ((bf2f(u4.y >> 16) + bf2f(u5.y >> 16)) + (bf2f(u6.y >> 16) + bf2f(u7.y >> 16)));
    }
    for (; k + 4 <= cnt; k += 4) {
        uint2 u0 = hs2v[(size_t)my[k]     * 16 + q];
        uint2 u1 = hs2v[(size_t)my[k + 1] * 16 + q];
        uint2 u2 = hs2v[(size_t)my[k + 2] * 16 + q];
        uint2 u3 = hs2v[(size_t)my[k + 3] * 16 + q];
        a0 += (bf2f(u0.x & 0xFFFF) + bf2f(u1.x & 0xFFFF)) + (bf2f(u2.x & 0xFFFF) + bf2f(u3.x & 0xFFFF));
        a1 += (bf2f(u0.x >> 16) + bf2f(u1.x >> 16)) + (bf2f(u2.x >> 16) + bf2f(u3.x >> 16));
        a2 += (bf2f(u0.y & 0xFFFF) + bf2f(u1.y & 0xFFFF)) + (bf2f(u2.y & 0xFFFF) + bf2f(u3.y & 0xFFFF));
        a3 += (bf2f(u0.y >> 16) + bf2f(u1.y >> 16)) + (bf2f(u2.y >> 16) + bf2f(u3.y >> 16));
    }
    for (; k < cnt; ++k) {
        uint2 u = hs2v[(size_t)my[k] * 16 + q];
        a0 += bf2f(u.x & 0xFFFF);
        a1 += bf2f(u.x >> 16);
        a2 += bf2f(u.y & 0xFFFF);
        a3 += bf2f(u.y >> 16);
    }
    int oc = *ovf_cnt;                                // broadcast load; 0 in practice
    if (oc > 0) {
        oc = oc < OVF_CAP ? oc : OVF_CAP;
        for (int i = 0; i < oc; ++i) {
            if (ovf[2 * i + 1] == d) {
                uint2 u = hs2v[(size_t)ovf[2 * i] * 16 + q];
                a0 += bf2f(u.x & 0xFFFF);
                a1 += bf2f(u.x >> 16);
                a2 += bf2f(u.y & 0xFFFF);
                a3 += bf2f(u.y >> 16);
            }
        }
    }
    uint2 us = hs2v[(size_t)d * 16 + q];              // self loop
    float dd = z4[d].w;
    float4 bb = *(const float4*)&b2[4 * q];
    float4 o;
    o.x = dd * (a0 + bf2f(us.x & 0xFFFF)) + bb.x;
    o.y = dd * (a1 + bf2f(us.x >> 16)) + bb.y;
    o.z = dd * (a2 + bf2f(us.y & 0xFFFF)) + bb.z;
    o.w = dd * (a3 + bf2f(us.y >> 16)) + bb.w;
    *(float4*)&out[(size_t)d * OUTC + 4 * q] = o;     // 256B coalesced per node
}

static inline size_t align256(size_t v) { return (v + 255) & ~(size_t)255; }

extern "C" void kernel_launch(void* const* d_in, const int* in_sizes, int n_in,
                              void* d_out, int out_size, void* d_ws, size_t ws_size,
                              hipStream_t stream) {
    const float* x  = (const float*)d_in[0];
    const int*   ei = (const int*)d_in[1];
    const float* W1 = (const float*)d_in[2];
    const float* b1 = (const float*)d_in[3];
    const float* W2 = (const float*)d_in[4];
    const float* b2 = (const float*)d_in[5];
    float* out = (float*)d_out;

    const int N = in_sizes[0] / INC;
    const int E = in_sizes[1] / 2;
    const int* src = ei;
    const int* dst = ei + E;
    const bool u16 = (N <= 65535);
    const int NCB = (N + 255) >> 8;

    char* ws = (char*)d_ws;
    size_t off = 0;
    int*    cursor  = (int*)(ws + off);    off += align256((size_t)N * 4);
    float4* z4      = (float4*)(ws + off); off += align256((size_t)N * 16);
    int*    cbcur   = (int*)(ws + off);    off += (size_t)NCBMAX * 4;      // zeroed with ovf_cnt
    int*    ovf_cnt = (int*)(ws + off);    off += 256;
    int*    ovf     = (int*)(ws + off);    off += (size_t)OVF_CAP * 8;
    unsigned int* part = (unsigned int*)(ws + off);
    off += align256(u16 ? (size_t)NCB * CAP8K * 4 : 0);
    void*   bucket  = (void*)(ws + off);
    off += align256(u16 ? (size_t)NCB * 256 * BCAP * 2 : (size_t)N * BCAP * 4);
    unsigned short* hs2b = (unsigned short*)(ws + off); off += (size_t)N * OUTC * 2;
    const uint2* hs2v = (const uint2*)hs2b;

    const int B = 256;

    if (u16) {
        hipMemsetAsync(cbcur, 0, (size_t)NCBMAX * 4 + 256, stream);        // cbcur + ovf_cnt
        int NB = (E + 256 * KPT - 1) / (256 * KPT);
        place2_kernel<<<NB, B, 0, stream>>>(src, dst, E, NCB, cbcur, part, ovf, ovf_cnt);
        bin_kernel<<<NCB, B, 0, stream>>>(part, cbcur, x, N, cursor,
                                          (unsigned short*)bucket, z4, ovf, ovf_cnt);
    } else {
        hipMemsetAsync(cursor, 0, (size_t)N * sizeof(int), stream);
        hipMemsetAsync(ovf_cnt, 0, 64, stream);
        int grid = (E + B * EPT - 1) / (B * EPT);
        int T = grid * B;
        fill_bucket_kernel<int><<<grid, B, 0, stream>>>(src, dst, E, T, cursor, (int*)bucket,
                                                        ovf, ovf_cnt);
        z4_kernel<<<(N + B - 1) / B, B, 0, stream>>>(x, cursor, z4, N);
    }

    // ---- fused layer-1 gather + hidden GEMM (bf16 out; l1-ovf inlined) ----
    if (u16)
        hidden_kernel<unsigned short><<<(N + NT - 1) / NT, 256, 0, stream>>>(
            (const unsigned short*)bucket, cursor, z4, W1, b1, W2, hs2b, N, ovf, ovf_cnt);
    else
        hidden_kernel<int><<<(N + NT - 1) / NT, 256, 0, stream>>>(
            (const int*)bucket, cursor, z4, W1, b1, W2, hs2b, N, ovf, ovf_cnt);

    // ---- layer 2 gather (LDS-staged, 4 nodes/wave, uint2 loads; l2-ovf inlined) ----
    if (u16)
        gather2_kernel<unsigned short><<<(N + 15) / 16, B, 0, stream>>>(
            cursor, (const unsigned short*)bucket, hs2v, z4, b2, out, N, ovf, ovf_cnt);
    else
        gather2_kernel<int><<<(N + 15) / 16, B, 0, stream>>>(
            cursor, (const int*)bucket, hs2v, z4, b2, out, N, ovf, ovf_cnt);
}

// Round 15
// 137.826 us; speedup vs baseline: 1.4902x; 1.0006x over previous
//
#include <hip/hip_runtime.h>
#include <hip/hip_bf16.h>

#define HID 128
#define OUTC 64
#define INC 3
#define BCAP 64        // bucket capacity per node (storage only; degree is exact)
#define OVF_CAP 8192   // overflow edge list capacity (expected usage: 0)
#define NT 64          // nodes per block in hidden GEMM
#define NCBMAX 256     // max coarse buckets (N<=65535 -> NCB<=256)
#define CAP8K 8192     // slots per coarse bucket in part[] (mean 4082, 64 sigma headroom)
#define KPT 8          // edges per thread in place2
#define EPT 4          // legacy path

static __device__ __forceinline__ unsigned short f2bf(float f) {
    __hip_bfloat16 b = __float2bfloat16(f);
    return *reinterpret_cast<unsigned short*>(&b);
}
static __device__ __forceinline__ float bf2f(unsigned short u) {
    __hip_bfloat16 b = *reinterpret_cast<__hip_bfloat16*>(&u);
    return __bfloat162float(b);
}

// ================= capacity-based counting-sort bucket build (N <= 65535 path) =================
// [proven rounds 11-14]

__global__ __launch_bounds__(256) void place2_kernel(const int* __restrict__ src,
                                                     const int* __restrict__ dst, int E, int NCB,
                                                     int* __restrict__ cbcur,
                                                     unsigned int* __restrict__ part,
                                                     int* __restrict__ ovf, int* __restrict__ ovf_cnt) {
    __shared__ int lhist[NCBMAX];
    __shared__ int lbase[NCBMAX];
    int t = threadIdx.x;
    int s0 = blockIdx.x * (256 * KPT);
    for (int i = t; i < NCBMAX; i += 256) lhist[i] = 0;
    __syncthreads();

    unsigned pk[KPT];
    int cbv[KPT];
    bool val[KPT];
#pragma unroll
    for (int i = 0; i < KPT; ++i) {
        int e = s0 + t + i * 256;                 // coalesced
        val[i] = (e < E);
        if (val[i]) {
            int d = dst[e], s = src[e];
            cbv[i] = d >> 8;
            pk[i] = (unsigned)s | ((unsigned)(d & 255) << 16);
            atomicAdd(&lhist[cbv[i]], 1);
        }
    }
    __syncthreads();
    for (int i = t; i < NCB; i += 256) {
        int c = lhist[i];
        lbase[i] = c ? atomicAdd(&cbcur[i], c) : 0;   // reserve contiguous range
        lhist[i] = 0;                                  // reuse as local offset
    }
    __syncthreads();
#pragma unroll
    for (int i = 0; i < KPT; ++i) {
        if (val[i]) {
            int cb = cbv[i];
            int p = atomicAdd(&lhist[cb], 1);
            int slot = lbase[cb] + p;
            if (slot < CAP8K) {
                part[(size_t)cb * CAP8K + slot] = pk[i];
            } else {                                   // impossible in practice; exact fallback
                int o = atomicAdd(ovf_cnt, 1);
                if (o < OVF_CAP) {
                    ovf[2 * o] = (int)(pk[i] & 0xFFFF);
                    ovf[2 * o + 1] = cb * 256 + (int)((pk[i] >> 16) & 0xFF);
                }
            }
        }
    }
}

__global__ __launch_bounds__(256) void bin_kernel(const unsigned int* __restrict__ part,
                                                  const int* __restrict__ cbcur,
                                                  const float* __restrict__ x, int N,
                                                  int* __restrict__ cursor,
                                                  unsigned short* __restrict__ bucket,
                                                  float4* __restrict__ z4,
                                                  int* __restrict__ ovf, int* __restrict__ ovf_cnt) {
    __shared__ int lcnt[256];
    __shared__ unsigned short lbuck[256 * BCAP];   // 32 KB
    int cb = blockIdx.x, t = threadIdx.x;
    lcnt[t] = 0;
    __syncthreads();
    int cnt = cbcur[cb];
    cnt = cnt < CAP8K ? cnt : CAP8K;
    size_t start = (size_t)cb * CAP8K;
    for (int i = t; i < cnt; i += 256) {
        unsigned pk = part[start + i];
        int s = pk & 0xFFFF;
        int ln = (pk >> 16) & 0xFF;
        int p = atomicAdd(&lcnt[ln], 1);
        if (p < BCAP) {
            lbuck[ln * BCAP + p] = (unsigned short)s;
        } else {
            int o = atomicAdd(ovf_cnt, 1);
            if (o < OVF_CAP) { ovf[2 * o] = s; ovf[2 * o + 1] = cb * 256 + ln; }
        }
    }
    __syncthreads();
    int d = cb * 256 + t;
    if (d < N) {
        int deg = lcnt[t];                         // exact degree (incl. >BCAP spill)
        cursor[d] = deg;
        float dd = rsqrtf((float)(deg + 1));       // +1 = self loop
        z4[d] = make_float4(dd * x[3 * d], dd * x[3 * d + 1], dd * x[3 * d + 2], dd);
    }
    const uint4* lsrc = (const uint4*)lbuck;
    uint4* gdst = (uint4*)(bucket + (size_t)cb * 256 * BCAP);
    for (int i = t; i < (256 * BCAP * 2) / 16; i += 256) gdst[i] = lsrc[i];  // dense copy
}

// ================= legacy path (N > 65535): atomic fill + z4 =================

template <typename IT>
__global__ void fill_bucket_kernel(const int* __restrict__ src, const int* __restrict__ dst, int E,
                                   int T, int* __restrict__ cursor, IT* __restrict__ bucket,
                                   int* __restrict__ ovf, int* __restrict__ ovf_cnt) {
    int tid = blockIdx.x * blockDim.x + threadIdx.x;
    int d[EPT], s[EPT], p[EPT];
    bool v[EPT];
#pragma unroll
    for (int k = 0; k < EPT; ++k) {
        int e = tid + k * T;
        v[k] = (e < E);
        d[k] = v[k] ? dst[e] : 0;
        s[k] = v[k] ? src[e] : 0;
    }
#pragma unroll
    for (int k = 0; k < EPT; ++k)
        if (v[k]) p[k] = atomicAdd(&cursor[d[k]], 1);
#pragma unroll
    for (int k = 0; k < EPT; ++k) {
        if (v[k]) {
            if (p[k] < BCAP) {
                bucket[(size_t)d[k] * BCAP + p[k]] = (IT)s[k];
            } else {
                int o = atomicAdd(ovf_cnt, 1);
                if (o < OVF_CAP) { ovf[2 * o] = s[k]; ovf[2 * o + 1] = d[k]; }
            }
        }
    }
}

__global__ void z4_kernel(const float* __restrict__ x, const int* __restrict__ cursor,
                          float4* __restrict__ z4, int N) {
    int i = blockIdx.x * blockDim.x + threadIdx.x;
    if (i < N) {
        float dd = rsqrtf((float)(cursor[i] + 1));
        z4[i] = make_float4(dd * x[3 * i], dd * x[3 * i + 1], dd * x[3 * i + 2], dd);
    }
}

// ==== fused hidden: layer-1 gather + relu(u@W1+b1) @ W2 GEMM, bf16 out   [proven round 14] ====

template <typename IT>
__global__ __launch_bounds__(256) void hidden_kernel(const IT* __restrict__ bucket,
                                                     const int* __restrict__ cursor,
                                                     const float4* __restrict__ z4,
                                                     const float* __restrict__ W1,
                                                     const float* __restrict__ b1,
                                                     const float* __restrict__ W2,
                                                     unsigned short* __restrict__ hs2b, int N,
                                                     const int* __restrict__ ovf,
                                                     const int* __restrict__ ovf_cnt) {
    __shared__ float h_s[HID][NT];       // 32 KB, k-major; first 192 floats alias u_s in stage 1
    __shared__ float w_s[HID * OUTC];    // 32 KB
    float* u_s = &h_s[0][0];             // [64][3] agg parking, 768 B
    int t = threadIdx.x;
    int base = blockIdx.x * NT;

    for (int i = t; i < HID * OUTC; i += 256) w_s[i] = W2[i];

    // stage 1a: gather agg for the block's 64 nodes
    {
        int g = (t & 63) & 15;           // node group within wave
        int r = (t & 63) >> 4;           // 0..3 split of the bucket list
        int n = (t >> 6) * 16 + g;       // wave w owns nodes w*16..w*16+15
        int d = base + n;
        float p0 = 0.f, p1 = 0.f, p2 = 0.f;
        if (d < N) {
            int cnt = cursor[d];
            cnt = cnt < BCAP ? cnt : BCAP;
            for (int k = r; k < cnt; k += 4) {
                int s = (int)bucket[(size_t)d * BCAP + k];
                float4 zv = z4[s];
                p0 += zv.x; p1 += zv.y; p2 += zv.z;
            }
        }
        // combine the 4 per-node partials (lanes l, l^16, l^32, l^48)
        p0 += __shfl_xor(p0, 16, 64); p0 += __shfl_xor(p0, 32, 64);
        p1 += __shfl_xor(p1, 16, 64); p1 += __shfl_xor(p1, 32, 64);
        p2 += __shfl_xor(p2, 16, 64); p2 += __shfl_xor(p2, 32, 64);
        if (r == 0 && d < N) {
            int oc = *ovf_cnt;                        // broadcast load; 0 in practice
            if (oc > 0) {
                oc = oc < OVF_CAP ? oc : OVF_CAP;
                for (int i = 0; i < oc; ++i) {
                    if (ovf[2 * i + 1] == d) {
                        float4 zs = z4[ovf[2 * i]];
                        p0 += zs.x; p1 += zs.y; p2 += zs.z;
                    }
                }
            }
            u_s[n * 3 + 0] = p0;
            u_s[n * 3 + 1] = p1;
            u_s[n * 3 + 2] = p2;
        }
    }
    __syncthreads();

    // stage 1b: u into registers (4 threads per node read the same agg)
    int n = t & 63;
    int d = base + n;
    float u0 = 0.f, u1 = 0.f, u2 = 0.f;
    if (d < N) {
        float a0 = u_s[n * 3], a1 = u_s[n * 3 + 1], a2 = u_s[n * 3 + 2];
        float4 zv = z4[d];
        float dd = zv.w;
        u0 = dd * (a0 + zv.x);
        u1 = dd * (a1 + zv.y);
        u2 = dd * (a2 + zv.z);
    }
    __syncthreads();                     // all u_s reads done before h_s writes

    // stage 1c: h = relu(u @ W1 + b1)
    {
        int k0 = t >> 6;
#pragma unroll
        for (int i = 0; i < HID / 4; ++i) {
            int k = k0 + 4 * i;
            float v = u0 * W1[k] + u1 * W1[HID + k] + u2 * W1[2 * HID + k] + b1[k];
            h_s[k][n] = fmaxf(v, 0.f);
        }
    }
    __syncthreads();

    // stage 2: 16x16 thread grid, 4x4 register tile
    int tx = t & 15, ty = t >> 4;
    float acc[4][4] = {};
#pragma unroll 8
    for (int k = 0; k < HID; ++k) {
        float4 hv = *(const float4*)&h_s[k][ty * 4];
        float4 wv = *(const float4*)&w_s[k * OUTC + tx * 4];
        float hr[4] = {hv.x, hv.y, hv.z, hv.w};
        float wr[4] = {wv.x, wv.y, wv.z, wv.w};
#pragma unroll
        for (int r = 0; r < 4; ++r)
#pragma unroll
            for (int c = 0; c < 4; ++c) acc[r][c] = fmaf(hr[r], wr[c], acc[r][c]);
    }

#pragma unroll
    for (int r = 0; r < 4; ++r) {
        int nn = ty * 4 + r;
        int dd_i = base + nn;
        if (dd_i < N) {
            float dd = z4[dd_i].w;
            ushort4 o;
            o.x = f2bf(dd * acc[r][0]);
            o.y = f2bf(dd * acc[r][1]);
            o.z = f2bf(dd * acc[r][2]);
            o.w = f2bf(dd * acc[r][3]);
            *(ushort4*)&hs2b[(size_t)dd_i * OUTC + tx * 4] = o;
        }
    }
}

// ======== layer-2 gather: LDS-staged lists, 8 nodes/wave, uint4 (8-feature) loads ========
// third step of the proven 64->32->16-lane progression; no cross-lane ops;
// source ids from LDS broadcast (uniform per 8-lane group); l2-ovf inlined

#define ACC8(u)                                                        \
    do {                                                               \
        a0 += bf2f((u).x & 0xFFFF); a1 += bf2f((u).x >> 16);           \
        a2 += bf2f((u).y & 0xFFFF); a3 += bf2f((u).y >> 16);           \
        a4 += bf2f((u).z & 0xFFFF); a5 += bf2f((u).z >> 16);           \
        a6 += bf2f((u).w & 0xFFFF); a7 += bf2f((u).w >> 16);           \
    } while (0)

template <typename IT>
__global__ __launch_bounds__(256) void gather2_kernel(const int* __restrict__ cursor,
                                                      const IT* __restrict__ bucket,
                                                      const uint4* __restrict__ hs2q,
                                                      const float4* __restrict__ z4,
                                                      const float* __restrict__ b2,
                                                      float* __restrict__ out, int N,
                                                      const int* __restrict__ ovf,
                                                      const int* __restrict__ ovf_cnt) {
    __shared__ int slist[32 * BCAP];                  // 8 KB: 32 nodes' source lists
    int t = threadIdx.x;
    int base = blockIdx.x * 32;                       // 32 nodes per block
    int lim = (N - base) * BCAP;                      // entries available
    int total = 32 * BCAP;
    if (lim > total) lim = total;
    for (int i = t; i < lim; i += 256) slist[i] = (int)bucket[(size_t)base * BCAP + i];
    __syncthreads();

    int g = t >> 3;                                   // group 0..31 -> node
    int q = t & 7;                                    // lane -> feature octet (8q..8q+7)
    int d = base + g;
    if (d >= N) return;
    int cnt = cursor[d];
    cnt = cnt < BCAP ? cnt : BCAP;
    const int* my = &slist[g * BCAP];
    float a0 = 0.f, a1 = 0.f, a2 = 0.f, a3 = 0.f, a4 = 0.f, a5 = 0.f, a6 = 0.f, a7 = 0.f;
    int k = 0;
    for (; k + 8 <= cnt; k += 8) {                    // 8 independent 16B row loads in flight
        uint4 u0 = hs2q[(size_t)my[k]     * 8 + q];
        uint4 u1 = hs2q[(size_t)my[k + 1] * 8 + q];
        uint4 u2 = hs2q[(size_t)my[k + 2] * 8 + q];
        uint4 u3 = hs2q[(size_t)my[k + 3] * 8 + q];
        uint4 u4 = hs2q[(size_t)my[k + 4] * 8 + q];
        uint4 u5 = hs2q[(size_t)my[k + 5] * 8 + q];
        uint4 u6 = hs2q[(size_t)my[k + 6] * 8 + q];
        uint4 u7 = hs2q[(size_t)my[k + 7] * 8 + q];
        ACC8(u0); ACC8(u1); ACC8(u2); ACC8(u3);
        ACC8(u4); ACC8(u5); ACC8(u6); ACC8(u7);
    }
    for (; k + 4 <= cnt; k += 4) {
        uint4 u0 = hs2q[(size_t)my[k]     * 8 + q];
        uint4 u1 = hs2q[(size_t)my[k + 1] * 8 + q];
        uint4 u2 = hs2q[(size_t)my[k + 2] * 8 + q];
        uint4 u3 = hs2q[(size_t)my[k + 3] * 8 + q];
        ACC8(u0); ACC8(u1); ACC8(u2); ACC8(u3);
    }
    for (; k < cnt; ++k) {
        uint4 u = hs2q[(size_t)my[k] * 8 + q];
        ACC8(u);
    }
    int oc = *ovf_cnt;                                // broadcast load; 0 in practice
    if (oc > 0) {
        oc = oc < OVF_CAP ? oc : OVF_CAP;
        for (int i = 0; i < oc; ++i) {
            if (ovf[2 * i + 1] == d) {
                uint4 u = hs2q[(size_t)ovf[2 * i] * 8 + q];
                ACC8(u);
            }
        }
    }
    uint4 us = hs2q[(size_t)d * 8 + q];               // self loop
    float dd = z4[d].w;
    float4 bbl = *(const float4*)&b2[8 * q];
    float4 bbh = *(const float4*)&b2[8 * q + 4];
    float4 ol, oh;
    ol.x = dd * (a0 + bf2f(us.x & 0xFFFF)) + bbl.x;
    ol.y = dd * (a1 + bf2f(us.x >> 16)) + bbl.y;
    ol.z = dd * (a2 + bf2f(us.y & 0xFFFF)) + bbl.z;
    ol.w = dd * (a3 + bf2f(us.y >> 16)) + bbl.w;
    oh.x = dd * (a4 + bf2f(us.z & 0xFFFF)) + bbh.x;
    oh.y = dd * (a5 + bf2f(us.z >> 16)) + bbh.y;
    oh.z = dd * (a6 + bf2f(us.w & 0xFFFF)) + bbh.z;
    oh.w = dd * (a7 + bf2f(us.w >> 16)) + bbh.w;
    *(float4*)&out[(size_t)d * OUTC + 8 * q] = ol;    // 256B coalesced per node
    *(float4*)&out[(size_t)d * OUTC + 8 * q + 4] = oh;
}

static inline size_t align256(size_t v) { return (v + 255) & ~(size_t)255; }

extern "C" void kernel_launch(void* const* d_in, const int* in_sizes, int n_in,
                              void* d_out, int out_size, void* d_ws, size_t ws_size,
                              hipStream_t stream) {
    const float* x  = (const float*)d_in[0];
    const int*   ei = (const int*)d_in[1];
    const float* W1 = (const float*)d_in[2];
    const float* b1 = (const float*)d_in[3];
    const float* W2 = (const float*)d_in[4];
    const float* b2 = (const float*)d_in[5];
    float* out = (float*)d_out;

    const int N = in_sizes[0] / INC;
    const int E = in_sizes[1] / 2;
    const int* src = ei;
    const int* dst = ei + E;
    const bool u16 = (N <= 65535);
    const int NCB = (N + 255) >> 8;

    char* ws = (char*)d_ws;
    size_t off = 0;
    int*    cursor  = (int*)(ws + off);    off += align256((size_t)N * 4);
    float4* z4      = (float4*)(ws + off); off += align256((size_t)N * 16);
    int*    cbcur   = (int*)(ws + off);    off += (size_t)NCBMAX * 4;      // zeroed with ovf_cnt
    int*    ovf_cnt = (int*)(ws + off);    off += 256;
    int*    ovf     = (int*)(ws + off);    off += (size_t)OVF_CAP * 8;
    unsigned int* part = (unsigned int*)(ws + off);
    off += align256(u16 ? (size_t)NCB * CAP8K * 4 : 0);
    void*   bucket  = (void*)(ws + off);
    off += align256(u16 ? (size_t)NCB * 256 * BCAP * 2 : (size_t)N * BCAP * 4);
    unsigned short* hs2b = (unsigned short*)(ws + off); off += (size_t)N * OUTC * 2;
    const uint4* hs2q = (const uint4*)hs2b;

    const int B = 256;

    if (u16) {
        hipMemsetAsync(cbcur, 0, (size_t)NCBMAX * 4 + 256, stream);        // cbcur + ovf_cnt
        int NB = (E + 256 * KPT - 1) / (256 * KPT);
        place2_kernel<<<NB, B, 0, stream>>>(src, dst, E, NCB, cbcur, part, ovf, ovf_cnt);
        bin_kernel<<<NCB, B, 0, stream>>>(part, cbcur, x, N, cursor,
                                          (unsigned short*)bucket, z4, ovf, ovf_cnt);
    } else {
        hipMemsetAsync(cursor, 0, (size_t)N * sizeof(int), stream);
        hipMemsetAsync(ovf_cnt, 0, 64, stream);
        int grid = (E + B * EPT - 1) / (B * EPT);
        int T = grid * B;
        fill_bucket_kernel<int><<<grid, B, 0, stream>>>(src, dst, E, T, cursor, (int*)bucket,
                                                        ovf, ovf_cnt);
        z4_kernel<<<(N + B - 1) / B, B, 0, stream>>>(x, cursor, z4, N);
    }

    // ---- fused layer-1 gather + hidden GEMM (bf16 out; l1-ovf inlined) ----
    if (u16)
        hidden_kernel<unsigned short><<<(N + NT - 1) / NT, 256, 0, stream>>>(
            (const unsigned short*)bucket, cursor, z4, W1, b1, W2, hs2b, N, ovf, ovf_cnt);
    else
        hidden_kernel<int><<<(N + NT - 1) / NT, 256, 0, stream>>>(
            (const int*)bucket, cursor, z4, W1, b1, W2, hs2b, N, ovf, ovf_cnt);

    // ---- layer 2 gather (LDS-staged, 8 nodes/wave, uint4 loads; l2-ovf inlined) ----
    if (u16)
        gather2_kernel<unsigned short><<<(N + 31) / 32, B, 0, stream>>>(
            cursor, (const unsigned short*)bucket, hs2q, z4, b2, out, N, ovf, ovf_cnt);
    else
        gather2_kernel<int><<<(N + 31) / 32, B, 0, stream>>>(
            cursor, (const int*)bucket, hs2q, z4, b2, out, N, ovf, ovf_cnt);
}